// Round 4
// baseline (706.262 us; speedup 1.0000x reference)
//
#include <hip/hip_runtime.h>

// Problem constants (fixed by the reference file)
#define IN_DIM   128
#define OUT_DIM  128
#define ATTN_DIM 64
#define N_RELV   401          // 2*N_REL+1
#define N_NODE   50000
#define N_EDGE   500000
#define N_QUERY  64
#define N_DT     731          // delta_tau in [-365, 365]

__device__ __forceinline__ int clampi(int v, int lo, int hi) {
    return v < lo ? lo : (v > hi ? hi : v);
}

// ---------------------------------------------------------------------------
// Detect whether integer inputs are int64 (JAX x64 mode) or int32.
// For int64 edges, every odd int32 word is a high word in {0,-1}.
// flag[0] = 1 if int64, 0 if int32.
// ---------------------------------------------------------------------------
__global__ __launch_bounds__(256) void detect_kernel(
    const int* __restrict__ edges, int* __restrict__ flag)
{
    __shared__ int bad;
    if (threadIdx.x == 0) bad = 0;
    __syncthreads();
    for (int i = threadIdx.x; i < 1000; i += 256) {
        const int w = edges[2 * i + 1];
        if (w != 0 && w != -1) bad = 1;   // benign race
    }
    __syncthreads();
    if (threadIdx.x == 0) flag[0] = (bad == 0) ? 1 : 0;
}

// ---------------------------------------------------------------------------
// XsWs[n][a] = sum_d hidden[n][d] * Ws[d][a]   (50000 x 64 fp32)
// 4 nodes per 256-thread block, one wave per node. Exact grid.
// ---------------------------------------------------------------------------
__global__ __launch_bounds__(256) void node_proj_kernel(
    const float* __restrict__ hidden, const float* __restrict__ Ws,
    float* __restrict__ XsWs)
{
    const int wid  = threadIdx.x >> 6;
    const int lane = threadIdx.x & 63;
    const int n    = blockIdx.x * 4 + wid;

    __shared__ float h[4][IN_DIM];
    const float2 v = ((const float2*)(hidden + (size_t)n * IN_DIM))[lane];
    h[wid][2 * lane]     = v.x;
    h[wid][2 * lane + 1] = v.y;
    __syncthreads();

    float acc = 0.f;
    #pragma unroll 8
    for (int d = 0; d < IN_DIM; ++d)
        acc += h[wid][d] * Ws[d * ATTN_DIM + lane];
    XsWs[(size_t)n * ATTN_DIM + lane] = acc;
}

// ---------------------------------------------------------------------------
// XrWr[r][a] = sum_d rela_embed[r][d] * Wr[d][a]   (401 x 64)
// ---------------------------------------------------------------------------
__global__ __launch_bounds__(64) void rel_proj_kernel(
    const float* __restrict__ rela, const float* __restrict__ Wr,
    float* __restrict__ XrWr)
{
    const int r    = blockIdx.x;
    const int lane = threadIdx.x;

    __shared__ float h[IN_DIM];
    const float2 v = ((const float2*)(rela + (size_t)r * IN_DIM))[lane];
    h[2 * lane]     = v.x;
    h[2 * lane + 1] = v.y;
    __syncthreads();

    float acc = 0.f;
    #pragma unroll 8
    for (int d = 0; d < IN_DIM; ++d)
        acc += h[d] * Wr[d * ATTN_DIM + lane];
    XrWr[(size_t)r * ATTN_DIM + lane] = acc;
}

// ---------------------------------------------------------------------------
// Xqr[q][a] = rela_embed[q_rel[q]] @ Wqr_W + Wqr_b   (64 x 64)
// ---------------------------------------------------------------------------
__global__ __launch_bounds__(64) void qr_proj_kernel(
    const float* __restrict__ rela, const int* __restrict__ q_rel,
    const float* __restrict__ W, const float* __restrict__ bias,
    const int* __restrict__ flag, float* __restrict__ Xqr)
{
    const int q    = blockIdx.x;
    const int lane = threadIdx.x;
    const int i64  = flag[0];
    const int rel  = clampi(q_rel[i64 ? 2 * q : q], 0, N_RELV - 1);

    __shared__ float h[IN_DIM];
    const float2 v = ((const float2*)(rela + (size_t)rel * IN_DIM))[lane];
    h[2 * lane]     = v.x;
    h[2 * lane + 1] = v.y;
    __syncthreads();

    float acc = bias[lane];
    #pragma unroll 8
    for (int d = 0; d < IN_DIM; ++d)
        acc += h[d] * W[d * ATTN_DIM + lane];
    Xqr[(size_t)q * ATTN_DIM + lane] = acc;
}

// ---------------------------------------------------------------------------
// For each delta in [-365,365]:
//   htab[i][d] = wt1[d]*dt + bt1[d] + sin(wt2[d]*dt + bt2[d])
//   Xtau[i][a] = sum_d htab[i][d] * Wtau[d][a]
// ---------------------------------------------------------------------------
__global__ __launch_bounds__(64) void tau_proj_kernel(
    const float* __restrict__ wt1, const float* __restrict__ bt1,
    const float* __restrict__ wt2, const float* __restrict__ bt2,
    const float* __restrict__ Wtau,
    float* __restrict__ Xtau, float* __restrict__ htab)
{
    const int i    = blockIdx.x;
    const int lane = threadIdx.x;
    const float dt = (float)(i - 365);

    __shared__ float h[IN_DIM];
    for (int d = lane; d < IN_DIM; d += 64)
        h[d] = wt1[d] * dt + bt1[d] + sinf(wt2[d] * dt + bt2[d]);
    __syncthreads();

    htab[(size_t)i * IN_DIM + lane]      = h[lane];
    htab[(size_t)i * IN_DIM + lane + 64] = h[lane + 64];

    float acc = 0.f;
    #pragma unroll 8
    for (int d = 0; d < IN_DIM; ++d)
        acc += h[d] * Wtau[d * ATTN_DIM + lane];
    Xtau[(size_t)i * ATTN_DIM + lane] = acc;
}

// ---------------------------------------------------------------------------
// Per edge: alpha = sigmoid(relu(XsWs[sub]+XrWr[rel]+Xqr[r]+Xtau[di]) . w_alpha + b)
// atomicAdd alpha * (hs + hr + h_tau) into agg[obj] (= d_out, fp32).
// One wave per edge; 4 edges per 256-thread block. Exact grid.
// XsWs may be null (ws too small) -> compute hs@Ws inline.
// ---------------------------------------------------------------------------
__global__ __launch_bounds__(256) void edge_kernel(
    const int* __restrict__ edges, const int* __restrict__ q_tau,
    const float* __restrict__ XsWs, const float* __restrict__ Ws,
    const float* __restrict__ XrWr,
    const float* __restrict__ Xqr,  const float* __restrict__ Xtau,
    const float* __restrict__ htab,
    const float* __restrict__ hidden, const float* __restrict__ rela,
    const float* __restrict__ w_alpha_W, const float* __restrict__ w_alpha_b,
    const int* __restrict__ flag, float* __restrict__ agg)
{
    const int wid  = threadIdx.x >> 6;
    const int lane = threadIdx.x & 63;
    const int e    = blockIdx.x * 4 + wid;
    const int i64  = flag[0];

    int r, rel, tau, sub, obj;
    if (i64) {
        const int* E = edges + (size_t)e * 14;   // int64 rows: low words at 2k
        r = E[0]; rel = E[4]; tau = E[8]; sub = E[10]; obj = E[12];
    } else {
        const int* E = edges + (size_t)e * 7;
        r = E[0]; rel = E[2]; tau = E[4]; sub = E[5]; obj = E[6];
    }
    r   = clampi(r,   0, N_QUERY - 1);
    rel = clampi(rel, 0, N_RELV - 1);
    sub = clampi(sub, 0, N_NODE - 1);
    obj = clampi(obj, 0, N_NODE - 1);

    const int tq = q_tau[i64 ? 2 * r : r];
    if (tau < 0) tau = tq;
    const int di = clampi(tau - tq + 365, 0, N_DT - 1);

    // Message inputs (also reused for inline projection fallback)
    const float2 a = ((const float2*)(hidden + (size_t)sub * IN_DIM))[lane];
    const float2 b = ((const float2*)(rela   + (size_t)rel * IN_DIM))[lane];
    const float2 t = ((const float2*)(htab   + (size_t)di  * IN_DIM))[lane];

    float pre_s;
    if (XsWs != nullptr) {
        pre_s = XsWs[(size_t)sub * ATTN_DIM + lane];
    } else {
        __shared__ float hrow[4][IN_DIM];
        hrow[wid][2 * lane]     = a.x;
        hrow[wid][2 * lane + 1] = a.y;
        __syncthreads();                 // uniform branch: all 256 arrive
        float acc = 0.f;
        #pragma unroll 8
        for (int d = 0; d < IN_DIM; ++d)
            acc += hrow[wid][d] * Ws[d * ATTN_DIM + lane];
        pre_s = acc;
        __syncthreads();
    }

    float pre = pre_s
              + XrWr[(size_t)rel * ATTN_DIM + lane]
              + Xqr [(size_t)r   * ATTN_DIM + lane]
              + Xtau[(size_t)di  * ATTN_DIM + lane];
    pre = fmaxf(pre, 0.f);

    float v = pre * w_alpha_W[lane];
    #pragma unroll
    for (int off = 32; off > 0; off >>= 1)
        v += __shfl_down(v, off, 64);
    v = __shfl(v, 0, 64);
    const float alpha = 1.f / (1.f + __expf(-(v + w_alpha_b[0])));

    float* dst = agg + (size_t)obj * IN_DIM;
    atomicAdd(dst + 2 * lane,     alpha * (a.x + b.x + t.x));
    atomicAdd(dst + 2 * lane + 1, alpha * (a.y + b.y + t.y));
}

// ---------------------------------------------------------------------------
// In-place: io[n][:] = io[n][:] @ Wh   (row staged through LDS first)
// ---------------------------------------------------------------------------
__global__ __launch_bounds__(128) void out_gemm_kernel(
    float* __restrict__ io, const float* __restrict__ Wh)
{
    const int n   = blockIdx.x;
    const int tid = threadIdx.x;

    __shared__ float m[IN_DIM];
    m[tid] = io[(size_t)n * IN_DIM + tid];
    __syncthreads();

    float acc = 0.f;
    #pragma unroll 8
    for (int d = 0; d < IN_DIM; ++d)
        acc += m[d] * Wh[d * OUT_DIM + tid];
    io[(size_t)n * OUT_DIM + tid] = acc;
}

extern "C" void kernel_launch(void* const* d_in, const int* in_sizes, int n_in,
                              void* d_out, int out_size, void* d_ws, size_t ws_size,
                              hipStream_t stream)
{
    // setup_inputs() order:
    // 0 q_sub(unused) 1 q_rel 2 q_tau 3 hidden 4 edges 5 n_node(scalar)
    // 6 old_nodes_new_idx(unused) 7 rela_embed 8 Ws 9 Wr 10 Wqr_W 11 Wqr_b
    // 12 Wtau 13 w_alpha_W 14 w_alpha_b 15 Wh 16 wt1 17 bt1 18 wt2 19 bt2
    const int*   q_rel  = (const int*)d_in[1];
    const int*   q_tau  = (const int*)d_in[2];
    const float* hidden = (const float*)d_in[3];
    const int*   edges  = (const int*)d_in[4];
    const float* rela   = (const float*)d_in[7];
    const float* Ws     = (const float*)d_in[8];
    const float* Wr     = (const float*)d_in[9];
    const float* WqrW   = (const float*)d_in[10];
    const float* Wqrb   = (const float*)d_in[11];
    const float* Wtau   = (const float*)d_in[12];
    const float* waW    = (const float*)d_in[13];
    const float* wab    = (const float*)d_in[14];
    const float* Wh     = (const float*)d_in[15];
    const float* wt1    = (const float*)d_in[16];
    const float* bt1    = (const float*)d_in[17];
    const float* wt2    = (const float*)d_in[18];
    const float* bt2    = (const float*)d_in[19];
    float* out = (float*)d_out;   // fp32 output; doubles as agg accumulator

    // Workspace layout (fp32 tables first). ~13.5 MB total with XsWs.
    char*  wsb  = (char*)d_ws;
    int*   flag = (int*)wsb;                             // 16 ints (pad to 64 B)
    float* XrWr = (float*)(wsb + 64);                    // 401*64
    float* Xqr  = XrWr + (size_t)N_RELV * ATTN_DIM;      // 64*64
    float* Xtau = Xqr  + (size_t)N_QUERY * ATTN_DIM;     // 731*64
    float* htab = Xtau + (size_t)N_DT * ATTN_DIM;        // 731*128
    float* XsWs = htab + (size_t)N_DT * IN_DIM;          // 50000*64 (optional)

    const size_t need_full = 64
        + ((size_t)N_RELV * ATTN_DIM + (size_t)N_QUERY * ATTN_DIM
           + (size_t)N_DT * ATTN_DIM + (size_t)N_DT * IN_DIM
           + (size_t)N_NODE * ATTN_DIM) * sizeof(float);
    const bool have_xsws = (ws_size >= need_full);

    // agg accumulates in d_out (fp32): zero it (harness poisons to 0xAA).
    hipMemsetAsync(out, 0, (size_t)out_size * sizeof(float), stream);

    detect_kernel   <<<1,          256, 0, stream>>>(edges, flag);
    if (have_xsws)
        node_proj_kernel<<<N_NODE / 4, 256, 0, stream>>>(hidden, Ws, XsWs);
    rel_proj_kernel <<<N_RELV,     64,  0, stream>>>(rela, Wr, XrWr);
    qr_proj_kernel  <<<N_QUERY,    64,  0, stream>>>(rela, q_rel, WqrW, Wqrb, flag, Xqr);
    tau_proj_kernel <<<N_DT,       64,  0, stream>>>(wt1, bt1, wt2, bt2, Wtau, Xtau, htab);
    edge_kernel     <<<N_EDGE / 4, 256, 0, stream>>>(edges, q_tau,
                                                     have_xsws ? XsWs : nullptr, Ws,
                                                     XrWr, Xqr, Xtau, htab,
                                                     hidden, rela, waW, wab, flag, out);
    out_gemm_kernel <<<N_NODE,     128, 0, stream>>>(out, Wh);
}

// Round 6
// 689.698 us; speedup vs baseline: 1.0240x; 1.0240x over previous
//
#include <hip/hip_runtime.h>

// Problem constants (fixed by the reference file)
#define IN_DIM   128
#define OUT_DIM  128
#define ATTN_DIM 64
#define N_RELV   401          // 2*N_REL+1
#define N_NODE   50000
#define N_EDGE   500000
#define N_QUERY  64
#define N_DT     731          // delta_tau in [-365, 365]
#define REC_W    192          // fused record: 64 bf16 attn + 128 bf16 msg

typedef unsigned short ushort_t;
typedef unsigned int   uint_t;

__device__ __forceinline__ int clampi(int v, int lo, int hi) {
    return v < lo ? lo : (v > hi ? hi : v);
}
__device__ __forceinline__ float bu2f(ushort_t u) {
    union { uint_t i; float f; } v; v.i = ((uint_t)u) << 16; return v.f;
}
// fp32 -> bf16 bits, round-to-nearest-even (inputs are finite; no NaN path)
__device__ __forceinline__ ushort_t f2bu(float f) {
    union { float f; uint_t i; } v; v.f = f;
    const uint_t x = v.i;
    return (ushort_t)((x + 0x7fffu + ((x >> 16) & 1u)) >> 16);
}

// ---------------------------------------------------------------------------
// int64-vs-int32 detection (JAX x64 guard). flag[0]=1 if int64.
// ---------------------------------------------------------------------------
__global__ __launch_bounds__(256) void detect_kernel(
    const int* __restrict__ edges, int* __restrict__ flag)
{
    __shared__ int bad;
    if (threadIdx.x == 0) bad = 0;
    __syncthreads();
    for (int i = threadIdx.x; i < 1000; i += 256) {
        const int w = edges[2 * i + 1];
        if (w != 0 && w != -1) bad = 1;   // benign race
    }
    __syncthreads();
    if (threadIdx.x == 0) flag[0] = (bad == 0) ? 1 : 0;
}

// ===========================================================================
// FAST PATH: fused bf16 records + Wh folded into the edge pass.
// ===========================================================================

// ---------------------------------------------------------------------------
// node_rec[n] = [ (hidden[n]@Ws) as 64 bf16 | (hidden[n]@Wh) as 128 bf16 ]
// Block: 192 threads (t<64: attn GEMV; t>=64: msg GEMV), 32 nodes/block,
// 4-node inner unroll; Ws/Wh staged once per block in LDS as bf16.
// ---------------------------------------------------------------------------
#define NB_NODES 32
__global__ __launch_bounds__(192) void node_rec_kernel(
    const float* __restrict__ hidden, const float* __restrict__ Ws,
    const float* __restrict__ Wh, ushort_t* __restrict__ node_rec)
{
    const int tid = threadIdx.x;
    __shared__ ushort_t WsL[IN_DIM * ATTN_DIM];   // 16 KB
    __shared__ ushort_t WhL[IN_DIM * OUT_DIM];    // 32 KB
    __shared__ float    h4[4][IN_DIM];            // 2 KB

    for (int i = tid; i < IN_DIM * ATTN_DIM; i += 192) WsL[i] = f2bu(Ws[i]);
    for (int i = tid; i < IN_DIM * OUT_DIM;  i += 192) WhL[i] = f2bu(Wh[i]);
    __syncthreads();

    const int n_base = blockIdx.x * NB_NODES;
    for (int k = 0; k < NB_NODES; k += 4) {
        const int n0 = n_base + k;
        // stage 4 hidden rows
        for (int j = 0; j < 4; ++j) {
            const int n = n0 + j;
            if (tid < IN_DIM && n < N_NODE)
                h4[j][tid] = hidden[(size_t)n * IN_DIM + tid];
        }
        __syncthreads();

        float acc0 = 0.f, acc1 = 0.f, acc2 = 0.f, acc3 = 0.f;
        if (tid < ATTN_DIM) {
            #pragma unroll 4
            for (int d = 0; d < IN_DIM; ++d) {
                const float w = bu2f(WsL[d * ATTN_DIM + tid]);
                acc0 += w * h4[0][d]; acc1 += w * h4[1][d];
                acc2 += w * h4[2][d]; acc3 += w * h4[3][d];
            }
            for (int j = 0; j < 4; ++j) {
                const int n = n0 + j;
                if (n < N_NODE) {
                    const float a = (j == 0) ? acc0 : (j == 1) ? acc1 : (j == 2) ? acc2 : acc3;
                    node_rec[(size_t)n * REC_W + tid] = f2bu(a);
                }
            }
        } else {
            const int c = tid - 64;          // msg column 0..127
            #pragma unroll 4
            for (int d = 0; d < IN_DIM; ++d) {
                const float w = bu2f(WhL[d * OUT_DIM + c]);
                acc0 += w * h4[0][d]; acc1 += w * h4[1][d];
                acc2 += w * h4[2][d]; acc3 += w * h4[3][d];
            }
            for (int j = 0; j < 4; ++j) {
                const int n = n0 + j;
                if (n < N_NODE) {
                    const float a = (j == 0) ? acc0 : (j == 1) ? acc1 : (j == 2) ? acc2 : acc3;
                    node_rec[(size_t)n * REC_W + 64 + c] = f2bu(a);
                }
            }
        }
        __syncthreads();
    }
}

// ---------------------------------------------------------------------------
// rel_rec[r] = [ rela[r]@Wr (64 bf16) | rela[r]@Wh (128 bf16) ]
// ---------------------------------------------------------------------------
__global__ __launch_bounds__(128) void rel_rec_kernel(
    const float* __restrict__ rela, const float* __restrict__ Wr,
    const float* __restrict__ Wh, ushort_t* __restrict__ rel_rec)
{
    const int r = blockIdx.x, tid = threadIdx.x;
    __shared__ float h[IN_DIM];
    h[tid] = rela[(size_t)r * IN_DIM + tid];
    __syncthreads();

    if (tid < ATTN_DIM) {
        float a = 0.f;
        #pragma unroll 8
        for (int d = 0; d < IN_DIM; ++d) a += h[d] * Wr[d * ATTN_DIM + tid];
        rel_rec[(size_t)r * REC_W + tid] = f2bu(a);
    }
    float m = 0.f;
    #pragma unroll 8
    for (int d = 0; d < IN_DIM; ++d) m += h[d] * Wh[d * OUT_DIM + tid];
    rel_rec[(size_t)r * REC_W + 64 + tid] = f2bu(m);
}

// ---------------------------------------------------------------------------
// dt_rec[i] = [ h_tau(i)@Wtau (64 bf16) | h_tau(i)@Wh (128 bf16) ]
// h_tau(i)[d] = wt1[d]*dt + bt1[d] + sin(wt2[d]*dt + bt2[d]),  dt = i-365
// ---------------------------------------------------------------------------
__global__ __launch_bounds__(128) void dt_rec_kernel(
    const float* __restrict__ wt1, const float* __restrict__ bt1,
    const float* __restrict__ wt2, const float* __restrict__ bt2,
    const float* __restrict__ Wtau, const float* __restrict__ Wh,
    ushort_t* __restrict__ dt_rec)
{
    const int i = blockIdx.x, tid = threadIdx.x;
    const float dt = (float)(i - 365);
    __shared__ float h[IN_DIM];
    h[tid] = wt1[tid] * dt + bt1[tid] + sinf(wt2[tid] * dt + bt2[tid]);
    __syncthreads();

    if (tid < ATTN_DIM) {
        float a = 0.f;
        #pragma unroll 8
        for (int d = 0; d < IN_DIM; ++d) a += h[d] * Wtau[d * ATTN_DIM + tid];
        dt_rec[(size_t)i * REC_W + tid] = f2bu(a);
    }
    float m = 0.f;
    #pragma unroll 8
    for (int d = 0; d < IN_DIM; ++d) m += h[d] * Wh[d * OUT_DIM + tid];
    dt_rec[(size_t)i * REC_W + 64 + tid] = f2bu(m);
}

// ---------------------------------------------------------------------------
// Xqr[q][a] = rela[q_rel[q]] @ Wqr_W + Wqr_b   (64x64 bf16)
// ---------------------------------------------------------------------------
__global__ __launch_bounds__(64) void qr_tab_kernel(
    const float* __restrict__ rela, const int* __restrict__ q_rel,
    const float* __restrict__ W, const float* __restrict__ bias,
    const int* __restrict__ flag, ushort_t* __restrict__ Xqr)
{
    const int q = blockIdx.x, lane = threadIdx.x;
    const int i64 = flag[0];
    const int rel = clampi(q_rel[i64 ? 2 * q : q], 0, N_RELV - 1);

    __shared__ float h[IN_DIM];
    const float2 v = ((const float2*)(rela + (size_t)rel * IN_DIM))[lane];
    h[2 * lane] = v.x; h[2 * lane + 1] = v.y;
    __syncthreads();

    float acc = bias[lane];
    #pragma unroll 8
    for (int d = 0; d < IN_DIM; ++d) acc += h[d] * W[d * ATTN_DIM + lane];
    Xqr[(size_t)q * ATTN_DIM + lane] = f2bu(acc);
}

// ---------------------------------------------------------------------------
// Fused edge kernel: alpha from bf16 attn tables; atomicAdd
// alpha*(hsWh+hrWh+htWh) directly into out (fp32). One wave per edge.
// ---------------------------------------------------------------------------
__global__ __launch_bounds__(256) void edge_fused_kernel(
    const int* __restrict__ edges, const int* __restrict__ q_tau,
    const ushort_t* __restrict__ node_rec, const ushort_t* __restrict__ rel_rec,
    const ushort_t* __restrict__ dt_rec,  const ushort_t* __restrict__ Xqr,
    const float* __restrict__ w_alpha_W, const float* __restrict__ w_alpha_b,
    const int* __restrict__ flag, float* __restrict__ out)
{
    const int wid  = threadIdx.x >> 6;
    const int lane = threadIdx.x & 63;
    const int e    = blockIdx.x * 4 + wid;   // exact grid
    const int i64  = flag[0];

    int r, rel, tau, sub, obj;
    if (i64) {
        const int* E = edges + (size_t)e * 14;
        r = E[0]; rel = E[4]; tau = E[8]; sub = E[10]; obj = E[12];
    } else {
        const int* E = edges + (size_t)e * 7;
        r = E[0]; rel = E[2]; tau = E[4]; sub = E[5]; obj = E[6];
    }
    r   = clampi(r,   0, N_QUERY - 1);
    rel = clampi(rel, 0, N_RELV - 1);
    sub = clampi(sub, 0, N_NODE - 1);
    obj = clampi(obj, 0, N_NODE - 1);

    const int tq = q_tau[i64 ? 2 * r : r];
    if (tau < 0) tau = tq;
    const int di = clampi(tau - tq + 365, 0, N_DT - 1);

    const ushort_t* NR = node_rec + (size_t)sub * REC_W;
    const ushort_t* RR = rel_rec  + (size_t)rel * REC_W;
    const ushort_t* DR = dt_rec   + (size_t)di  * REC_W;

    // attention pre-activation (bf16 tables)
    const float xs = bu2f(NR[lane]);
    const float xr = bu2f(RR[lane]);
    const float xt = bu2f(DR[lane]);
    const float xq = bu2f(Xqr[(size_t)r * ATTN_DIM + lane]);
    // message halves (packed bf16 pairs)
    const uint_t am = *(const uint_t*)(NR + 64 + 2 * lane);
    const uint_t bm = *(const uint_t*)(RR + 64 + 2 * lane);
    const uint_t tm = *(const uint_t*)(DR + 64 + 2 * lane);

    float pre = fmaxf(xs + xr + xq + xt, 0.f);
    float v = pre * w_alpha_W[lane];
    #pragma unroll
    for (int off = 32; off > 0; off >>= 1)
        v += __shfl_down(v, off, 64);
    v = __shfl(v, 0, 64);
    const float alpha = 1.f / (1.f + __expf(-(v + w_alpha_b[0])));

    const float mx = bu2f((ushort_t)(am & 0xffff)) + bu2f((ushort_t)(bm & 0xffff))
                   + bu2f((ushort_t)(tm & 0xffff));
    const float my = bu2f((ushort_t)(am >> 16)) + bu2f((ushort_t)(bm >> 16))
                   + bu2f((ushort_t)(tm >> 16));

    float* dst = out + (size_t)obj * OUT_DIM;
    atomicAdd(dst + 2 * lane,     alpha * mx);
    atomicAdd(dst + 2 * lane + 1, alpha * my);
}

// ===========================================================================
// FALLBACK PATH (round-4 pipeline, known-good) — used if ws is too small.
// ===========================================================================

__global__ __launch_bounds__(256) void node_proj_kernel(
    const float* __restrict__ hidden, const float* __restrict__ Ws,
    float* __restrict__ XsWs)
{
    const int wid  = threadIdx.x >> 6;
    const int lane = threadIdx.x & 63;
    const int n    = blockIdx.x * 4 + wid;

    __shared__ float h[4][IN_DIM];
    const float2 v = ((const float2*)(hidden + (size_t)n * IN_DIM))[lane];
    h[wid][2 * lane] = v.x; h[wid][2 * lane + 1] = v.y;
    __syncthreads();

    float acc = 0.f;
    #pragma unroll 8
    for (int d = 0; d < IN_DIM; ++d)
        acc += h[wid][d] * Ws[d * ATTN_DIM + lane];
    XsWs[(size_t)n * ATTN_DIM + lane] = acc;
}

__global__ __launch_bounds__(64) void rel_proj_kernel(
    const float* __restrict__ rela, const float* __restrict__ Wr,
    float* __restrict__ XrWr)
{
    const int r = blockIdx.x, lane = threadIdx.x;
    __shared__ float h[IN_DIM];
    const float2 v = ((const float2*)(rela + (size_t)r * IN_DIM))[lane];
    h[2 * lane] = v.x; h[2 * lane + 1] = v.y;
    __syncthreads();

    float acc = 0.f;
    #pragma unroll 8
    for (int d = 0; d < IN_DIM; ++d) acc += h[d] * Wr[d * ATTN_DIM + lane];
    XrWr[(size_t)r * ATTN_DIM + lane] = acc;
}

__global__ __launch_bounds__(64) void qr_proj_kernel(
    const float* __restrict__ rela, const int* __restrict__ q_rel,
    const float* __restrict__ W, const float* __restrict__ bias,
    const int* __restrict__ flag, float* __restrict__ Xqr)
{
    const int q = blockIdx.x, lane = threadIdx.x;
    const int i64 = flag[0];
    const int rel = clampi(q_rel[i64 ? 2 * q : q], 0, N_RELV - 1);

    __shared__ float h[IN_DIM];
    const float2 v = ((const float2*)(rela + (size_t)rel * IN_DIM))[lane];
    h[2 * lane] = v.x; h[2 * lane + 1] = v.y;
    __syncthreads();

    float acc = bias[lane];
    #pragma unroll 8
    for (int d = 0; d < IN_DIM; ++d) acc += h[d] * W[d * ATTN_DIM + lane];
    Xqr[(size_t)q * ATTN_DIM + lane] = acc;
}

__global__ __launch_bounds__(64) void tau_proj_kernel(
    const float* __restrict__ wt1, const float* __restrict__ bt1,
    const float* __restrict__ wt2, const float* __restrict__ bt2,
    const float* __restrict__ Wtau,
    float* __restrict__ Xtau, float* __restrict__ htab)
{
    const int i = blockIdx.x, lane = threadIdx.x;
    const float dt = (float)(i - 365);

    __shared__ float h[IN_DIM];
    for (int d = lane; d < IN_DIM; d += 64)
        h[d] = wt1[d] * dt + bt1[d] + sinf(wt2[d] * dt + bt2[d]);
    __syncthreads();

    htab[(size_t)i * IN_DIM + lane]      = h[lane];
    htab[(size_t)i * IN_DIM + lane + 64] = h[lane + 64];

    float acc = 0.f;
    #pragma unroll 8
    for (int d = 0; d < IN_DIM; ++d) acc += h[d] * Wtau[d * ATTN_DIM + lane];
    Xtau[(size_t)i * ATTN_DIM + lane] = acc;
}

__global__ __launch_bounds__(256) void edge_kernel(
    const int* __restrict__ edges, const int* __restrict__ q_tau,
    const float* __restrict__ XsWs, const float* __restrict__ Ws,
    const float* __restrict__ XrWr,
    const float* __restrict__ Xqr,  const float* __restrict__ Xtau,
    const float* __restrict__ htab,
    const float* __restrict__ hidden, const float* __restrict__ rela,
    const float* __restrict__ w_alpha_W, const float* __restrict__ w_alpha_b,
    const int* __restrict__ flag, float* __restrict__ agg)
{
    const int wid  = threadIdx.x >> 6;
    const int lane = threadIdx.x & 63;
    const int e    = blockIdx.x * 4 + wid;
    const int i64  = flag[0];

    int r, rel, tau, sub, obj;
    if (i64) {
        const int* E = edges + (size_t)e * 14;
        r = E[0]; rel = E[4]; tau = E[8]; sub = E[10]; obj = E[12];
    } else {
        const int* E = edges + (size_t)e * 7;
        r = E[0]; rel = E[2]; tau = E[4]; sub = E[5]; obj = E[6];
    }
    r   = clampi(r,   0, N_QUERY - 1);
    rel = clampi(rel, 0, N_RELV - 1);
    sub = clampi(sub, 0, N_NODE - 1);
    obj = clampi(obj, 0, N_NODE - 1);

    const int tq = q_tau[i64 ? 2 * r : r];
    if (tau < 0) tau = tq;
    const int di = clampi(tau - tq + 365, 0, N_DT - 1);

    const float2 a = ((const float2*)(hidden + (size_t)sub * IN_DIM))[lane];
    const float2 b = ((const float2*)(rela   + (size_t)rel * IN_DIM))[lane];
    const float2 t = ((const float2*)(htab   + (size_t)di  * IN_DIM))[lane];

    float pre_s;
    if (XsWs != nullptr) {
        pre_s = XsWs[(size_t)sub * ATTN_DIM + lane];
    } else {
        __shared__ float hrow[4][IN_DIM];
        hrow[wid][2 * lane]     = a.x;
        hrow[wid][2 * lane + 1] = a.y;
        __syncthreads();
        float acc = 0.f;
        #pragma unroll 8
        for (int d = 0; d < IN_DIM; ++d)
            acc += hrow[wid][d] * Ws[d * ATTN_DIM + lane];
        pre_s = acc;
        __syncthreads();
    }

    float pre = pre_s
              + XrWr[(size_t)rel * ATTN_DIM + lane]
              + Xqr [(size_t)r   * ATTN_DIM + lane]
              + Xtau[(size_t)di  * ATTN_DIM + lane];
    pre = fmaxf(pre, 0.f);

    float v = pre * w_alpha_W[lane];
    #pragma unroll
    for (int off = 32; off > 0; off >>= 1)
        v += __shfl_down(v, off, 64);
    v = __shfl(v, 0, 64);
    const float alpha = 1.f / (1.f + __expf(-(v + w_alpha_b[0])));

    float* dst = agg + (size_t)obj * IN_DIM;
    atomicAdd(dst + 2 * lane,     alpha * (a.x + b.x + t.x));
    atomicAdd(dst + 2 * lane + 1, alpha * (a.y + b.y + t.y));
}

__global__ __launch_bounds__(128) void out_gemm_kernel(
    float* __restrict__ io, const float* __restrict__ Wh)
{
    const int n = blockIdx.x, tid = threadIdx.x;
    __shared__ float m[IN_DIM];
    m[tid] = io[(size_t)n * IN_DIM + tid];
    __syncthreads();

    float acc = 0.f;
    #pragma unroll 8
    for (int d = 0; d < IN_DIM; ++d) acc += m[d] * Wh[d * OUT_DIM + tid];
    io[(size_t)n * OUT_DIM + tid] = acc;
}

// ===========================================================================
extern "C" void kernel_launch(void* const* d_in, const int* in_sizes, int n_in,
                              void* d_out, int out_size, void* d_ws, size_t ws_size,
                              hipStream_t stream)
{
    const int*   q_rel  = (const int*)d_in[1];
    const int*   q_tau  = (const int*)d_in[2];
    const float* hidden = (const float*)d_in[3];
    const int*   edges  = (const int*)d_in[4];
    const float* rela   = (const float*)d_in[7];
    const float* Ws     = (const float*)d_in[8];
    const float* Wr     = (const float*)d_in[9];
    const float* WqrW   = (const float*)d_in[10];
    const float* Wqrb   = (const float*)d_in[11];
    const float* Wtau   = (const float*)d_in[12];
    const float* waW    = (const float*)d_in[13];
    const float* wab    = (const float*)d_in[14];
    const float* Wh     = (const float*)d_in[15];
    const float* wt1    = (const float*)d_in[16];
    const float* bt1    = (const float*)d_in[17];
    const float* wt2    = (const float*)d_in[18];
    const float* bt2    = (const float*)d_in[19];
    float* out = (float*)d_out;   // fp32; accumulated via atomics

    char* wsb  = (char*)d_ws;
    int*  flag = (int*)wsb;       // 64 B reserved

    // Fast-path layout (bf16 records): ~19.7 MB
    ushort_t* XqrB     = (ushort_t*)(wsb + 64);              // 64*64
    ushort_t* rel_rec  = XqrB + (size_t)N_QUERY * ATTN_DIM;  // 401*192
    ushort_t* dt_rec   = rel_rec + (size_t)N_RELV * REC_W;   // 731*192
    ushort_t* node_rec = dt_rec + (size_t)N_DT * REC_W;      // 50000*192
    const size_t need_fast = 64 + 2 * ((size_t)N_QUERY * ATTN_DIM
        + ((size_t)N_RELV + N_DT + N_NODE) * REC_W);

    (void)hipMemsetAsync(out, 0, (size_t)out_size * sizeof(float), stream);
    detect_kernel<<<1, 256, 0, stream>>>(edges, flag);

    if (ws_size >= need_fast) {
        const int n_blocks = (N_NODE + NB_NODES - 1) / NB_NODES;
        node_rec_kernel<<<n_blocks, 192, 0, stream>>>(hidden, Ws, Wh, node_rec);
        rel_rec_kernel <<<N_RELV,   128, 0, stream>>>(rela, Wr, Wh, rel_rec);
        dt_rec_kernel  <<<N_DT,     128, 0, stream>>>(wt1, bt1, wt2, bt2, Wtau, Wh, dt_rec);
        qr_tab_kernel  <<<N_QUERY,  64,  0, stream>>>(rela, q_rel, WqrW, Wqrb, flag, XqrB);
        edge_fused_kernel<<<N_EDGE / 4, 256, 0, stream>>>(edges, q_tau, node_rec,
                                                          rel_rec, dt_rec, XqrB,
                                                          waW, wab, flag, out);
    } else {
        // Fallback (round-4 pipeline, fp32 tables, separate out GEMM)
        float* XrWr = (float*)(wsb + 64);
        float* Xqr  = XrWr + (size_t)N_RELV * ATTN_DIM;
        float* Xtau = Xqr  + (size_t)N_QUERY * ATTN_DIM;
        float* htab = Xtau + (size_t)N_DT * ATTN_DIM;
        float* XsWs = htab + (size_t)N_DT * IN_DIM;
        const size_t need_full = 64
            + ((size_t)N_RELV * ATTN_DIM + (size_t)N_QUERY * ATTN_DIM
               + (size_t)N_DT * ATTN_DIM + (size_t)N_DT * IN_DIM
               + (size_t)N_NODE * ATTN_DIM) * sizeof(float);
        const bool have_xsws = (ws_size >= need_full);

        if (have_xsws)
            node_proj_kernel<<<N_NODE / 4, 256, 0, stream>>>(hidden, Ws, XsWs);
        rel_proj_kernel <<<N_RELV,  64, 0, stream>>>(rela, Wr, XrWr);
        qr_proj_kernel  <<<N_QUERY, 64, 0, stream>>>(rela, q_rel, WqrW, Wqrb, flag, Xqr);
        tau_proj_kernel <<<N_DT,    64, 0, stream>>>(wt1, bt1, wt2, bt2, Wtau, Xtau, htab);
        edge_kernel     <<<N_EDGE / 4, 256, 0, stream>>>(edges, q_tau,
                                                         have_xsws ? XsWs : nullptr, Ws,
                                                         XrWr, Xqr, Xtau, htab,
                                                         hidden, rela, waW, wab, flag, out);
        out_gemm_kernel <<<N_NODE, 128, 0, stream>>>(out, Wh);
    }
}

// Round 7
// 416.440 us; speedup vs baseline: 1.6960x; 1.6562x over previous
//
#include <hip/hip_runtime.h>

#define IN_DIM   128
#define OUT_DIM  128
#define ATTN_DIM 64
#define N_RELV   401
#define N_NODE   50000
#define N_EDGE   500000
#define N_QUERY  64
#define N_DT     731
#define LDK      136      // 128 + 8 bf16 pad for LDS rows
#define NCH      196      // ceil(50000/256) scan chunks

typedef unsigned short ushort_t;
typedef unsigned int   uint_t;
typedef __attribute__((ext_vector_type(8))) short v8s;   // 8 bf16 (4 VGPRs)
typedef __attribute__((ext_vector_type(4))) float v4f;

__device__ __forceinline__ int clampi(int v, int lo, int hi) {
    return v < lo ? lo : (v > hi ? hi : v);
}
__device__ __forceinline__ float bu2f(ushort_t u) {
    union { uint_t i; float f; } v; v.i = ((uint_t)u) << 16; return v.f;
}
__device__ __forceinline__ ushort_t f2bu(float f) {   // RNE, finite inputs
    union { float f; uint_t i; } v; v.f = f;
    const uint_t x = v.i;
    return (ushort_t)((x + 0x7fffu + ((x >> 16) & 1u)) >> 16);
}

// edge parse (int32 vs int64 rows)
__device__ __forceinline__ void parse_edge(const int* __restrict__ edges, int e,
                                           int i64, int& r, int& rel, int& tau,
                                           int& sub, int& obj) {
    if (i64) {
        const int* E = edges + (size_t)e * 14;
        r = E[0]; rel = E[4]; tau = E[8]; sub = E[10]; obj = E[12];
    } else {
        const int* E = edges + (size_t)e * 7;
        r = E[0]; rel = E[2]; tau = E[4]; sub = E[5]; obj = E[6];
    }
    r   = clampi(r,   0, N_QUERY - 1);
    rel = clampi(rel, 0, N_RELV - 1);
    sub = clampi(sub, 0, N_NODE - 1);
    obj = clampi(obj, 0, N_NODE - 1);
}

// ---------------------------------------------------------------------------
__global__ __launch_bounds__(256) void detect_kernel(
    const int* __restrict__ edges, int* __restrict__ flag)
{
    __shared__ int bad;
    if (threadIdx.x == 0) bad = 0;
    __syncthreads();
    for (int i = threadIdx.x; i < 1000; i += 256) {
        const int w = edges[2 * i + 1];
        if (w != 0 && w != -1) bad = 1;
    }
    __syncthreads();
    if (threadIdx.x == 0) flag[0] = (bad == 0) ? 1 : 0;
}

// ---------------------------------------------------------------------------
// MFMA node projection: [node_attn | node_msg] = hidden @ [Ws | Wh]  (bf16 out)
// Block: 64 node rows, 4 waves; wave computes a 16-row stripe over 192 cols.
// ---------------------------------------------------------------------------
__global__ __launch_bounds__(256) void node_tab_mfma(
    const float* __restrict__ hidden, const float* __restrict__ Ws,
    const float* __restrict__ Wh,
    ushort_t* __restrict__ node_attn, ushort_t* __restrict__ node_msg)
{
    __shared__ ushort_t WT[192 * LDK];   // W^T as [n][k] bf16
    __shared__ ushort_t AS[64 * LDK];    // hidden rows as [m][k] bf16
    const int tid = threadIdx.x;
    const int nb  = blockIdx.x * 64;

    for (int i = tid; i < 192 * 128; i += 256) {
        const int k = i / 192, n = i % 192;
        const float w = (n < 64) ? Ws[k * 64 + n] : Wh[k * 128 + (n - 64)];
        WT[n * LDK + k] = f2bu(w);
    }
    for (int i = tid; i < 64 * 128; i += 256) {
        const int m = i / 128, k = i % 128;
        const int node = nb + m;
        AS[m * LDK + k] = f2bu(node < N_NODE ? hidden[(size_t)node * 128 + k] : 0.f);
    }
    __syncthreads();

    const int wid  = tid >> 6;
    const int lane = tid & 63;
    const int m16  = lane & 15;   // A row in tile / D col
    const int q    = lane >> 4;   // quad
    const int rb   = wid * 16;    // wave's block-row base

    v8s afr[4];
    #pragma unroll
    for (int c = 0; c < 4; ++c)
        afr[c] = *(const v8s*)&AS[(rb + m16) * LDK + 32 * c + 8 * q];

    #pragma unroll
    for (int t = 0; t < 12; ++t) {
        v4f acc = {0.f, 0.f, 0.f, 0.f};
        #pragma unroll
        for (int c = 0; c < 4; ++c) {
            const v8s bfr = *(const v8s*)&WT[(16 * t + m16) * LDK + 32 * c + 8 * q];
            acc = __builtin_amdgcn_mfma_f32_16x16x32_bf16(afr[c], bfr, acc, 0, 0, 0);
        }
        #pragma unroll
        for (int r = 0; r < 4; ++r) {
            const int node = nb + rb + 4 * q + r;   // D row = 4*quad + reg
            if (node < N_NODE) {
                const int col = 16 * t + m16;       // D col = lane&15
                if (col < 64) node_attn[(size_t)node * 64  + col]        = f2bu(acc[r]);
                else          node_msg [(size_t)node * 128 + (col - 64)] = f2bu(acc[r]);
            }
        }
    }
}

// ---------------------------------------------------------------------------
// rel tables: rel_attn = rela@Wr (bf16), rel_msg = rela@Wh (bf16)
// ---------------------------------------------------------------------------
__global__ __launch_bounds__(128) void rel_tab_kernel(
    const float* __restrict__ rela, const float* __restrict__ Wr,
    const float* __restrict__ Wh,
    ushort_t* __restrict__ rel_attn, ushort_t* __restrict__ rel_msg)
{
    const int r = blockIdx.x, tid = threadIdx.x;
    __shared__ float h[IN_DIM];
    h[tid] = rela[(size_t)r * IN_DIM + tid];
    __syncthreads();

    if (tid < ATTN_DIM) {
        float a = 0.f;
        #pragma unroll 8
        for (int d = 0; d < IN_DIM; ++d) a += h[d] * Wr[d * ATTN_DIM + tid];
        rel_attn[(size_t)r * ATTN_DIM + tid] = f2bu(a);
    }
    float m = 0.f;
    #pragma unroll 8
    for (int d = 0; d < IN_DIM; ++d) m += h[d] * Wh[d * OUT_DIM + tid];
    rel_msg[(size_t)r * OUT_DIM + tid] = f2bu(m);
}

// ---------------------------------------------------------------------------
// dt tables: h_tau(i) = wt1*dt + bt1 + sin(wt2*dt + bt2);  attn = @Wtau, msg = @Wh
// ---------------------------------------------------------------------------
__global__ __launch_bounds__(128) void dt_tab_kernel(
    const float* __restrict__ wt1, const float* __restrict__ bt1,
    const float* __restrict__ wt2, const float* __restrict__ bt2,
    const float* __restrict__ Wtau, const float* __restrict__ Wh,
    ushort_t* __restrict__ dt_attn, ushort_t* __restrict__ dt_msg)
{
    const int i = blockIdx.x, tid = threadIdx.x;
    const float dt = (float)(i - 365);
    __shared__ float h[IN_DIM];
    h[tid] = wt1[tid] * dt + bt1[tid] + sinf(wt2[tid] * dt + bt2[tid]);
    __syncthreads();

    if (tid < ATTN_DIM) {
        float a = 0.f;
        #pragma unroll 8
        for (int d = 0; d < IN_DIM; ++d) a += h[d] * Wtau[d * ATTN_DIM + tid];
        dt_attn[(size_t)i * ATTN_DIM + tid] = f2bu(a);
    }
    float m = 0.f;
    #pragma unroll 8
    for (int d = 0; d < IN_DIM; ++d) m += h[d] * Wh[d * OUT_DIM + tid];
    dt_msg[(size_t)i * OUT_DIM + tid] = f2bu(m);
}

// ---------------------------------------------------------------------------
__global__ __launch_bounds__(64) void qr_tab_kernel(
    const float* __restrict__ rela, const int* __restrict__ q_rel,
    const float* __restrict__ W, const float* __restrict__ bias,
    const int* __restrict__ flag, ushort_t* __restrict__ Xqr)
{
    const int q = blockIdx.x, lane = threadIdx.x;
    const int i64 = flag[0];
    const int rel = clampi(q_rel[i64 ? 2 * q : q], 0, N_RELV - 1);

    __shared__ float h[IN_DIM];
    const float2 v = ((const float2*)(rela + (size_t)rel * IN_DIM))[lane];
    h[2 * lane] = v.x; h[2 * lane + 1] = v.y;
    __syncthreads();

    float acc = bias[lane];
    #pragma unroll 8
    for (int d = 0; d < IN_DIM; ++d) acc += h[d] * W[d * ATTN_DIM + lane];
    Xqr[(size_t)q * ATTN_DIM + lane] = f2bu(acc);
}

// ---------------------------------------------------------------------------
// CSR build: histogram, two-level exclusive scan, cursor init
// ---------------------------------------------------------------------------
__global__ __launch_bounds__(256) void hist_kernel(
    const int* __restrict__ edges, const int* __restrict__ flag,
    int* __restrict__ deg)
{
    const int e = blockIdx.x * 256 + threadIdx.x;
    if (e >= N_EDGE) return;
    const int i64 = flag[0];
    int obj = i64 ? edges[(size_t)e * 14 + 12] : edges[(size_t)e * 7 + 6];
    obj = clampi(obj, 0, N_NODE - 1);
    atomicAdd(&deg[obj], 1);
}

__global__ __launch_bounds__(256) void scan_a_kernel(
    const int* __restrict__ deg, int* __restrict__ offs, int* __restrict__ chunksum)
{
    const int i = blockIdx.x * 256 + threadIdx.x;
    const int v = (i < N_NODE) ? deg[i] : 0;
    __shared__ int s[256];
    int acc = v;
    s[threadIdx.x] = acc; __syncthreads();
    #pragma unroll
    for (int off = 1; off < 256; off <<= 1) {
        const int t = (threadIdx.x >= off) ? s[threadIdx.x - off] : 0;
        __syncthreads();
        acc += t; s[threadIdx.x] = acc;
        __syncthreads();
    }
    if (i < N_NODE) offs[i] = acc - v;                 // chunk-exclusive
    if (threadIdx.x == 255) chunksum[blockIdx.x] = acc;
}

__global__ __launch_bounds__(256) void scan_b_kernel(
    const int* __restrict__ chunksum, int* __restrict__ chunkbase,
    int* __restrict__ offs)
{
    const int b = threadIdx.x;
    const int v = (b < NCH) ? chunksum[b] : 0;
    __shared__ int s[256];
    int acc = v;
    s[b] = acc; __syncthreads();
    #pragma unroll
    for (int off = 1; off < 256; off <<= 1) {
        const int t = (b >= off) ? s[b - off] : 0;
        __syncthreads();
        acc += t; s[b] = acc;
        __syncthreads();
    }
    if (b < NCH) chunkbase[b] = acc - v;
    if (b == 0) offs[N_NODE] = N_EDGE;
}

__global__ __launch_bounds__(256) void scan_c_kernel(
    const int* __restrict__ chunkbase, int* __restrict__ offs,
    int* __restrict__ cursor)
{
    const int i = blockIdx.x * 256 + threadIdx.x;
    if (i >= N_NODE) return;
    const int o = offs[i] + chunkbase[blockIdx.x];
    offs[i] = o;
    cursor[i] = o;
}

// ---------------------------------------------------------------------------
// Phase 1: per-edge alpha + scatter meta into CSR slot. One wave per edge.
// meta.x = sub | (di<<17)  (sub<2^17, di<2^10), meta.y = rel, metaW = alpha.
// ---------------------------------------------------------------------------
__global__ __launch_bounds__(256) void alpha_kernel(
    const int* __restrict__ edges, const int* __restrict__ q_tau,
    const ushort_t* __restrict__ node_attn, const ushort_t* __restrict__ rel_attn,
    const ushort_t* __restrict__ dt_attn,  const ushort_t* __restrict__ Xqr,
    const float* __restrict__ w_alpha_W, const float* __restrict__ w_alpha_b,
    const int* __restrict__ flag, int* __restrict__ cursor,
    int2* __restrict__ metaA, float* __restrict__ metaW)
{
    const int lane = threadIdx.x & 63;
    const int e    = blockIdx.x * 4 + (threadIdx.x >> 6);
    const int i64  = flag[0];

    int r, rel, tau, sub, obj;
    parse_edge(edges, e, i64, r, rel, tau, sub, obj);
    const int tq = q_tau[i64 ? 2 * r : r];
    if (tau < 0) tau = tq;
    const int di = clampi(tau - tq + 365, 0, N_DT - 1);

    const float xs = bu2f(node_attn[(size_t)sub * ATTN_DIM + lane]);
    const float xr = bu2f(rel_attn[(size_t)rel * ATTN_DIM + lane]);
    const float xt = bu2f(dt_attn[(size_t)di  * ATTN_DIM + lane]);
    const float xq = bu2f(Xqr[(size_t)r * ATTN_DIM + lane]);

    float v = fmaxf(xs + xr + xq + xt, 0.f) * w_alpha_W[lane];
    #pragma unroll
    for (int off = 32; off > 0; off >>= 1)
        v += __shfl_down(v, off, 64);

    if (lane == 0) {
        const float alpha = 1.f / (1.f + __expf(-(v + w_alpha_b[0])));
        const int pos = atomicAdd(&cursor[obj], 1);
        metaA[pos] = make_int2(sub | (di << 17), rel);
        metaW[pos] = alpha;
    }
}

// ---------------------------------------------------------------------------
// Phase 2: per-node aggregation (no atomics). One wave per node; lane owns
// output cols 2*lane, 2*lane+1. out = sum_e alpha_e*(node_msg+rel_msg+dt_msg).
// ---------------------------------------------------------------------------
__global__ __launch_bounds__(256) void agg_kernel(
    const int* __restrict__ offs, const int2* __restrict__ metaA,
    const float* __restrict__ metaW,
    const ushort_t* __restrict__ node_msg, const ushort_t* __restrict__ rel_msg,
    const ushort_t* __restrict__ dt_msg, float* __restrict__ out)
{
    const int lane = threadIdx.x & 63;
    const int n    = blockIdx.x * 4 + (threadIdx.x >> 6);   // exact grid

    const int lo = offs[n], hi = offs[n + 1];
    float a0 = 0.f, a1 = 0.f;
    for (int j = lo; j < hi; ++j) {
        const int2  m  = metaA[j];
        const float al = metaW[j];
        const int sub = m.x & 0x1FFFF;
        const int di  = m.x >> 17;
        const int rel = m.y;
        const uint_t am = *(const uint_t*)(node_msg + (size_t)sub * 128 + 2 * lane);
        const uint_t bm = *(const uint_t*)(rel_msg  + (size_t)rel * 128 + 2 * lane);
        const uint_t tm = *(const uint_t*)(dt_msg   + (size_t)di  * 128 + 2 * lane);
        a0 += al * (bu2f((ushort_t)(am & 0xffff)) + bu2f((ushort_t)(bm & 0xffff))
                  + bu2f((ushort_t)(tm & 0xffff)));
        a1 += al * (bu2f((ushort_t)(am >> 16)) + bu2f((ushort_t)(bm >> 16))
                  + bu2f((ushort_t)(tm >> 16)));
    }
    ((float2*)(out + (size_t)n * OUT_DIM))[lane] = make_float2(a0, a1);
}

// ---------------------------------------------------------------------------
// Fallback: single-pass atomic edge kernel (round-6 style, split tables).
// ---------------------------------------------------------------------------
__global__ __launch_bounds__(256) void edge_atomic_kernel(
    const int* __restrict__ edges, const int* __restrict__ q_tau,
    const ushort_t* __restrict__ node_attn, const ushort_t* __restrict__ node_msg,
    const ushort_t* __restrict__ rel_attn,  const ushort_t* __restrict__ rel_msg,
    const ushort_t* __restrict__ dt_attn,   const ushort_t* __restrict__ dt_msg,
    const ushort_t* __restrict__ Xqr,
    const float* __restrict__ w_alpha_W, const float* __restrict__ w_alpha_b,
    const int* __restrict__ flag, float* __restrict__ out)
{
    const int lane = threadIdx.x & 63;
    const int e    = blockIdx.x * 4 + (threadIdx.x >> 6);
    const int i64  = flag[0];

    int r, rel, tau, sub, obj;
    parse_edge(edges, e, i64, r, rel, tau, sub, obj);
    const int tq = q_tau[i64 ? 2 * r : r];
    if (tau < 0) tau = tq;
    const int di = clampi(tau - tq + 365, 0, N_DT - 1);

    const float xs = bu2f(node_attn[(size_t)sub * ATTN_DIM + lane]);
    const float xr = bu2f(rel_attn[(size_t)rel * ATTN_DIM + lane]);
    const float xt = bu2f(dt_attn[(size_t)di  * ATTN_DIM + lane]);
    const float xq = bu2f(Xqr[(size_t)r * ATTN_DIM + lane]);

    float v = fmaxf(xs + xr + xq + xt, 0.f) * w_alpha_W[lane];
    #pragma unroll
    for (int off = 32; off > 0; off >>= 1)
        v += __shfl_down(v, off, 64);
    v = __shfl(v, 0, 64);
    const float alpha = 1.f / (1.f + __expf(-(v + w_alpha_b[0])));

    const uint_t am = *(const uint_t*)(node_msg + (size_t)sub * 128 + 2 * lane);
    const uint_t bm = *(const uint_t*)(rel_msg  + (size_t)rel * 128 + 2 * lane);
    const uint_t tm = *(const uint_t*)(dt_msg   + (size_t)di  * 128 + 2 * lane);
    const float mx = bu2f((ushort_t)(am & 0xffff)) + bu2f((ushort_t)(bm & 0xffff))
                   + bu2f((ushort_t)(tm & 0xffff));
    const float my = bu2f((ushort_t)(am >> 16)) + bu2f((ushort_t)(bm >> 16))
                   + bu2f((ushort_t)(tm >> 16));

    float* dst = out + (size_t)obj * OUT_DIM;
    atomicAdd(dst + 2 * lane,     alpha * mx);
    atomicAdd(dst + 2 * lane + 1, alpha * my);
}

// ===========================================================================
extern "C" void kernel_launch(void* const* d_in, const int* in_sizes, int n_in,
                              void* d_out, int out_size, void* d_ws, size_t ws_size,
                              hipStream_t stream)
{
    const int*   q_rel  = (const int*)d_in[1];
    const int*   q_tau  = (const int*)d_in[2];
    const float* hidden = (const float*)d_in[3];
    const int*   edges  = (const int*)d_in[4];
    const float* rela   = (const float*)d_in[7];
    const float* Ws     = (const float*)d_in[8];
    const float* Wr     = (const float*)d_in[9];
    const float* WqrW   = (const float*)d_in[10];
    const float* Wqrb   = (const float*)d_in[11];
    const float* Wtau   = (const float*)d_in[12];
    const float* waW    = (const float*)d_in[13];
    const float* wab    = (const float*)d_in[14];
    const float* Wh     = (const float*)d_in[15];
    const float* wt1    = (const float*)d_in[16];
    const float* bt1    = (const float*)d_in[17];
    const float* wt2    = (const float*)d_in[18];
    const float* bt2    = (const float*)d_in[19];
    float* out = (float*)d_out;

    // --- workspace carve (256-B aligned chunks) ---
    char* p = (char*)d_ws;
    size_t off = 0;
    auto carve = [&](size_t bytes) {
        char* q = p + off;
        off = (off + bytes + 255) & ~(size_t)255;
        return q;
    };
    int*      flag      = (int*)     carve(64);
    ushort_t* XqrB      = (ushort_t*)carve((size_t)N_QUERY * ATTN_DIM * 2);
    ushort_t* rel_attn  = (ushort_t*)carve((size_t)N_RELV * ATTN_DIM * 2);
    ushort_t* rel_msg   = (ushort_t*)carve((size_t)N_RELV * OUT_DIM * 2);
    ushort_t* dt_attn   = (ushort_t*)carve((size_t)N_DT * ATTN_DIM * 2);
    ushort_t* dt_msg    = (ushort_t*)carve((size_t)N_DT * OUT_DIM * 2);
    ushort_t* node_attn = (ushort_t*)carve((size_t)N_NODE * ATTN_DIM * 2);
    ushort_t* node_msg  = (ushort_t*)carve((size_t)N_NODE * OUT_DIM * 2);
    const size_t need_tables = off;
    int*      deg       = (int*)     carve((size_t)N_NODE * 4);
    int*      offs      = (int*)     carve(((size_t)N_NODE + 1) * 4);
    int*      cursor    = (int*)     carve((size_t)N_NODE * 4);
    int*      chunksum  = (int*)     carve(256 * 4);
    int*      chunkbase = (int*)     carve(256 * 4);
    int2*     metaA     = (int2*)    carve((size_t)N_EDGE * 8);
    float*    metaW     = (float*)   carve((size_t)N_EDGE * 4);
    const size_t need_csr = off;

    detect_kernel<<<1, 256, 0, stream>>>(edges, flag);

    // shared precompute (both paths)
    node_tab_mfma<<<(N_NODE + 63) / 64, 256, 0, stream>>>(hidden, Ws, Wh,
                                                          node_attn, node_msg);
    rel_tab_kernel<<<N_RELV, 128, 0, stream>>>(rela, Wr, Wh, rel_attn, rel_msg);
    dt_tab_kernel <<<N_DT,   128, 0, stream>>>(wt1, bt1, wt2, bt2, Wtau, Wh,
                                               dt_attn, dt_msg);
    qr_tab_kernel <<<N_QUERY, 64, 0, stream>>>(rela, q_rel, WqrW, Wqrb, flag, XqrB);

    if (ws_size >= need_csr) {
        // CSR two-phase (no message atomics; out fully overwritten by agg)
        (void)hipMemsetAsync(deg, 0, (size_t)N_NODE * 4, stream);
        hist_kernel  <<<(N_EDGE + 255) / 256, 256, 0, stream>>>(edges, flag, deg);
        scan_a_kernel<<<NCH, 256, 0, stream>>>(deg, offs, chunksum);
        scan_b_kernel<<<1,   256, 0, stream>>>(chunksum, chunkbase, offs);
        scan_c_kernel<<<NCH, 256, 0, stream>>>(chunkbase, offs, cursor);
        alpha_kernel <<<N_EDGE / 4, 256, 0, stream>>>(edges, q_tau, node_attn,
                                                      rel_attn, dt_attn, XqrB,
                                                      waW, wab, flag, cursor,
                                                      metaA, metaW);
        agg_kernel   <<<N_NODE / 4, 256, 0, stream>>>(offs, metaA, metaW,
                                                      node_msg, rel_msg, dt_msg, out);
    } else {
        // fallback: atomic single-pass (needs only the tables; proven to fit)
        (void)hipMemsetAsync(out, 0, (size_t)out_size * sizeof(float), stream);
        edge_atomic_kernel<<<N_EDGE / 4, 256, 0, stream>>>(edges, q_tau,
                                                           node_attn, node_msg,
                                                           rel_attn, rel_msg,
                                                           dt_attn, dt_msg, XqrB,
                                                           waW, wab, flag, out);
    }
    (void)need_tables;
}

// Round 8
// 309.673 us; speedup vs baseline: 2.2807x; 1.3448x over previous
//
#include <hip/hip_runtime.h>

#define IN_DIM   128
#define OUT_DIM  128
#define ATTN_DIM 64
#define N_RELV   401
#define N_NODE   50000
#define N_EDGE   500000
#define N_QUERY  64
#define N_DT     731
#define LDK      136      // 128 + 8 bf16 pad for LDS rows
#define NCH      196      // ceil(50000/256) scan chunks

typedef unsigned short ushort_t;
typedef unsigned int   uint_t;
typedef __attribute__((ext_vector_type(8))) short v8s;   // 8 bf16 (4 VGPRs)
typedef __attribute__((ext_vector_type(4))) float v4f;

__device__ __forceinline__ int clampi(int v, int lo, int hi) {
    return v < lo ? lo : (v > hi ? hi : v);
}
__device__ __forceinline__ float bu2f(ushort_t u) {
    union { uint_t i; float f; } v; v.i = ((uint_t)u) << 16; return v.f;
}
__device__ __forceinline__ float blo(uint_t u) { return bu2f((ushort_t)(u & 0xffff)); }
__device__ __forceinline__ float bhi(uint_t u) { return bu2f((ushort_t)(u >> 16)); }
__device__ __forceinline__ ushort_t f2bu(float f) {   // RNE, finite inputs
    union { float f; uint_t i; } v; v.f = f;
    const uint_t x = v.i;
    return (ushort_t)((x + 0x7fffu + ((x >> 16) & 1u)) >> 16);
}

// edge parse (int32 vs int64 rows)
__device__ __forceinline__ void parse_edge(const int* __restrict__ edges, int e,
                                           int i64, int& r, int& rel, int& tau,
                                           int& sub, int& obj) {
    if (i64) {
        const int* E = edges + (size_t)e * 14;
        r = E[0]; rel = E[4]; tau = E[8]; sub = E[10]; obj = E[12];
    } else {
        const int* E = edges + (size_t)e * 7;
        r = E[0]; rel = E[2]; tau = E[4]; sub = E[5]; obj = E[6];
    }
    r   = clampi(r,   0, N_QUERY - 1);
    rel = clampi(rel, 0, N_RELV - 1);
    sub = clampi(sub, 0, N_NODE - 1);
    obj = clampi(obj, 0, N_NODE - 1);
}

// ---------------------------------------------------------------------------
__global__ __launch_bounds__(256) void detect_kernel(
    const int* __restrict__ edges, int* __restrict__ flag)
{
    __shared__ int bad;
    if (threadIdx.x == 0) bad = 0;
    __syncthreads();
    for (int i = threadIdx.x; i < 1000; i += 256) {
        const int w = edges[2 * i + 1];
        if (w != 0 && w != -1) bad = 1;
    }
    __syncthreads();
    if (threadIdx.x == 0) flag[0] = (bad == 0) ? 1 : 0;
}

// ---------------------------------------------------------------------------
// MFMA node projection: [node_attn | node_msg] = hidden @ [Ws | Wh]  (bf16 out)
// ---------------------------------------------------------------------------
__global__ __launch_bounds__(256) void node_tab_mfma(
    const float* __restrict__ hidden, const float* __restrict__ Ws,
    const float* __restrict__ Wh,
    ushort_t* __restrict__ node_attn, ushort_t* __restrict__ node_msg)
{
    __shared__ ushort_t WT[192 * LDK];   // W^T as [n][k] bf16
    __shared__ ushort_t AS[64 * LDK];    // hidden rows as [m][k] bf16
    const int tid = threadIdx.x;
    const int nb  = blockIdx.x * 64;

    for (int i = tid; i < 192 * 128; i += 256) {
        const int k = i / 192, n = i % 192;
        const float w = (n < 64) ? Ws[k * 64 + n] : Wh[k * 128 + (n - 64)];
        WT[n * LDK + k] = f2bu(w);
    }
    for (int i = tid; i < 64 * 128; i += 256) {
        const int m = i / 128, k = i % 128;
        const int node = nb + m;
        AS[m * LDK + k] = f2bu(node < N_NODE ? hidden[(size_t)node * 128 + k] : 0.f);
    }
    __syncthreads();

    const int wid  = tid >> 6;
    const int lane = tid & 63;
    const int m16  = lane & 15;
    const int q    = lane >> 4;
    const int rb   = wid * 16;

    v8s afr[4];
    #pragma unroll
    for (int c = 0; c < 4; ++c)
        afr[c] = *(const v8s*)&AS[(rb + m16) * LDK + 32 * c + 8 * q];

    #pragma unroll
    for (int t = 0; t < 12; ++t) {
        v4f acc = {0.f, 0.f, 0.f, 0.f};
        #pragma unroll
        for (int c = 0; c < 4; ++c) {
            const v8s bfr = *(const v8s*)&WT[(16 * t + m16) * LDK + 32 * c + 8 * q];
            acc = __builtin_amdgcn_mfma_f32_16x16x32_bf16(afr[c], bfr, acc, 0, 0, 0);
        }
        #pragma unroll
        for (int r = 0; r < 4; ++r) {
            const int node = nb + rb + 4 * q + r;
            if (node < N_NODE) {
                const int col = 16 * t + m16;
                if (col < 64) node_attn[(size_t)node * 64  + col]        = f2bu(acc[r]);
                else          node_msg [(size_t)node * 128 + (col - 64)] = f2bu(acc[r]);
            }
        }
    }
}

// ---------------------------------------------------------------------------
__global__ __launch_bounds__(128) void rel_tab_kernel(
    const float* __restrict__ rela, const float* __restrict__ Wr,
    const float* __restrict__ Wh,
    ushort_t* __restrict__ rel_attn, ushort_t* __restrict__ rel_msg)
{
    const int r = blockIdx.x, tid = threadIdx.x;
    __shared__ float h[IN_DIM];
    h[tid] = rela[(size_t)r * IN_DIM + tid];
    __syncthreads();

    if (tid < ATTN_DIM) {
        float a = 0.f;
        #pragma unroll 8
        for (int d = 0; d < IN_DIM; ++d) a += h[d] * Wr[d * ATTN_DIM + tid];
        rel_attn[(size_t)r * ATTN_DIM + tid] = f2bu(a);
    }
    float m = 0.f;
    #pragma unroll 8
    for (int d = 0; d < IN_DIM; ++d) m += h[d] * Wh[d * OUT_DIM + tid];
    rel_msg[(size_t)r * OUT_DIM + tid] = f2bu(m);
}

// ---------------------------------------------------------------------------
__global__ __launch_bounds__(128) void dt_tab_kernel(
    const float* __restrict__ wt1, const float* __restrict__ bt1,
    const float* __restrict__ wt2, const float* __restrict__ bt2,
    const float* __restrict__ Wtau, const float* __restrict__ Wh,
    ushort_t* __restrict__ dt_attn, ushort_t* __restrict__ dt_msg)
{
    const int i = blockIdx.x, tid = threadIdx.x;
    const float dt = (float)(i - 365);
    __shared__ float h[IN_DIM];
    h[tid] = wt1[tid] * dt + bt1[tid] + sinf(wt2[tid] * dt + bt2[tid]);
    __syncthreads();

    if (tid < ATTN_DIM) {
        float a = 0.f;
        #pragma unroll 8
        for (int d = 0; d < IN_DIM; ++d) a += h[d] * Wtau[d * ATTN_DIM + tid];
        dt_attn[(size_t)i * ATTN_DIM + tid] = f2bu(a);
    }
    float m = 0.f;
    #pragma unroll 8
    for (int d = 0; d < IN_DIM; ++d) m += h[d] * Wh[d * OUT_DIM + tid];
    dt_msg[(size_t)i * OUT_DIM + tid] = f2bu(m);
}

// ---------------------------------------------------------------------------
__global__ __launch_bounds__(64) void qr_tab_kernel(
    const float* __restrict__ rela, const int* __restrict__ q_rel,
    const float* __restrict__ W, const float* __restrict__ bias,
    const int* __restrict__ flag, ushort_t* __restrict__ Xqr)
{
    const int q = blockIdx.x, lane = threadIdx.x;
    const int i64 = flag[0];
    const int rel = clampi(q_rel[i64 ? 2 * q : q], 0, N_RELV - 1);

    __shared__ float h[IN_DIM];
    const float2 v = ((const float2*)(rela + (size_t)rel * IN_DIM))[lane];
    h[2 * lane] = v.x; h[2 * lane + 1] = v.y;
    __syncthreads();

    float acc = bias[lane];
    #pragma unroll 8
    for (int d = 0; d < IN_DIM; ++d) acc += h[d] * W[d * ATTN_DIM + lane];
    Xqr[(size_t)q * ATTN_DIM + lane] = f2bu(acc);
}

// ---------------------------------------------------------------------------
// CSR build
// ---------------------------------------------------------------------------
__global__ __launch_bounds__(256) void hist_kernel(
    const int* __restrict__ edges, const int* __restrict__ flag,
    int* __restrict__ deg)
{
    const int e = blockIdx.x * 256 + threadIdx.x;
    if (e >= N_EDGE) return;
    const int i64 = flag[0];
    int obj = i64 ? edges[(size_t)e * 14 + 12] : edges[(size_t)e * 7 + 6];
    obj = clampi(obj, 0, N_NODE - 1);
    atomicAdd(&deg[obj], 1);
}

__global__ __launch_bounds__(256) void scan_a_kernel(
    const int* __restrict__ deg, int* __restrict__ offs, int* __restrict__ chunksum)
{
    const int i = blockIdx.x * 256 + threadIdx.x;
    const int v = (i < N_NODE) ? deg[i] : 0;
    __shared__ int s[256];
    int acc = v;
    s[threadIdx.x] = acc; __syncthreads();
    #pragma unroll
    for (int off = 1; off < 256; off <<= 1) {
        const int t = (threadIdx.x >= off) ? s[threadIdx.x - off] : 0;
        __syncthreads();
        acc += t; s[threadIdx.x] = acc;
        __syncthreads();
    }
    if (i < N_NODE) offs[i] = acc - v;
    if (threadIdx.x == 255) chunksum[blockIdx.x] = acc;
}

__global__ __launch_bounds__(256) void scan_b_kernel(
    const int* __restrict__ chunksum, int* __restrict__ chunkbase,
    int* __restrict__ offs)
{
    const int b = threadIdx.x;
    const int v = (b < NCH) ? chunksum[b] : 0;
    __shared__ int s[256];
    int acc = v;
    s[b] = acc; __syncthreads();
    #pragma unroll
    for (int off = 1; off < 256; off <<= 1) {
        const int t = (b >= off) ? s[b - off] : 0;
        __syncthreads();
        acc += t; s[b] = acc;
        __syncthreads();
    }
    if (b < NCH) chunkbase[b] = acc - v;
    if (b == 0) offs[N_NODE] = N_EDGE;
}

__global__ __launch_bounds__(256) void scan_c_kernel(
    const int* __restrict__ chunkbase, int* __restrict__ offs,
    int* __restrict__ cursor)
{
    const int i = blockIdx.x * 256 + threadIdx.x;
    if (i >= N_NODE) return;
    const int o = offs[i] + chunkbase[blockIdx.x];
    offs[i] = o;
    cursor[i] = o;
}

// ---------------------------------------------------------------------------
// Phase 1: per-edge alpha. 16 lanes per edge (4 edges/wave, 16 edges/block).
// Lane g of a group covers attn cols 4g..4g+3 (one uint2 = 4 bf16 per table).
// meta.x = sub | (di<<17), meta.y = rel, metaW = alpha.
// ---------------------------------------------------------------------------
__global__ __launch_bounds__(256) void alpha_kernel(
    const int* __restrict__ edges, const int* __restrict__ q_tau,
    const ushort_t* __restrict__ node_attn, const ushort_t* __restrict__ rel_attn,
    const ushort_t* __restrict__ dt_attn,  const ushort_t* __restrict__ Xqr,
    const float* __restrict__ w_alpha_W, const float* __restrict__ w_alpha_b,
    const int* __restrict__ flag, int* __restrict__ cursor,
    int2* __restrict__ metaA, float* __restrict__ metaW)
{
    const int g   = threadIdx.x & 15;                 // lane within 16-group
    const int e   = blockIdx.x * 16 + (threadIdx.x >> 4);  // exact grid
    const int i64 = flag[0];

    int r, rel, tau, sub, obj;
    parse_edge(edges, e, i64, r, rel, tau, sub, obj);
    const int tq = q_tau[i64 ? 2 * r : r];
    if (tau < 0) tau = tq;
    const int di = clampi(tau - tq + 365, 0, N_DT - 1);

    const uint2 xs = *(const uint2*)(node_attn + (size_t)sub * ATTN_DIM + 4 * g);
    const uint2 xr = *(const uint2*)(rel_attn + (size_t)rel * ATTN_DIM + 4 * g);
    const uint2 xt = *(const uint2*)(dt_attn  + (size_t)di  * ATTN_DIM + 4 * g);
    const uint2 xq = *(const uint2*)(Xqr      + (size_t)r   * ATTN_DIM + 4 * g);
    const float4 w = *(const float4*)(w_alpha_W + 4 * g);

    const float s0 = blo(xs.x) + blo(xr.x) + blo(xt.x) + blo(xq.x);
    const float s1 = bhi(xs.x) + bhi(xr.x) + bhi(xt.x) + bhi(xq.x);
    const float s2 = blo(xs.y) + blo(xr.y) + blo(xt.y) + blo(xq.y);
    const float s3 = bhi(xs.y) + bhi(xr.y) + bhi(xt.y) + bhi(xq.y);

    float v = fmaxf(s0, 0.f) * w.x + fmaxf(s1, 0.f) * w.y
            + fmaxf(s2, 0.f) * w.z + fmaxf(s3, 0.f) * w.w;
    v += __shfl_down(v, 8, 16);
    v += __shfl_down(v, 4, 16);
    v += __shfl_down(v, 2, 16);
    v += __shfl_down(v, 1, 16);

    if (g == 0) {
        const float alpha = 1.f / (1.f + __expf(-(v + w_alpha_b[0])));
        const int pos = atomicAdd(&cursor[obj], 1);
        metaA[pos] = make_int2(sub | (di << 17), rel);
        metaW[pos] = alpha;
    }
}

// ---------------------------------------------------------------------------
// Phase 2: per-node aggregation, no atomics. One wave per node, lane owns
// cols 2*lane, 2*lane+1. Unroll-by-2 for memory-level parallelism.
// ---------------------------------------------------------------------------
__device__ __forceinline__ void agg_step(
    int2 m, float al, int lane,
    const ushort_t* __restrict__ node_msg, const ushort_t* __restrict__ rel_msg,
    const ushort_t* __restrict__ dt_msg, float& a0, float& a1)
{
    const int sub = m.x & 0x1FFFF;
    const int di  = m.x >> 17;
    const int rel = m.y;
    const uint_t am = *(const uint_t*)(node_msg + (size_t)sub * 128 + 2 * lane);
    const uint_t bm = *(const uint_t*)(rel_msg  + (size_t)rel * 128 + 2 * lane);
    const uint_t tm = *(const uint_t*)(dt_msg   + (size_t)di  * 128 + 2 * lane);
    a0 += al * (blo(am) + blo(bm) + blo(tm));
    a1 += al * (bhi(am) + bhi(bm) + bhi(tm));
}

__global__ __launch_bounds__(256) void agg_kernel(
    const int* __restrict__ offs, const int2* __restrict__ metaA,
    const float* __restrict__ metaW,
    const ushort_t* __restrict__ node_msg, const ushort_t* __restrict__ rel_msg,
    const ushort_t* __restrict__ dt_msg, float* __restrict__ out)
{
    const int lane = threadIdx.x & 63;
    const int n    = blockIdx.x * 4 + (threadIdx.x >> 6);   // exact grid

    const int lo = offs[n], hi = offs[n + 1];
    float a0 = 0.f, a1 = 0.f;
    int j = lo;
    for (; j + 1 < hi; j += 2) {
        const int2 m0 = metaA[j];     const float w0 = metaW[j];
        const int2 m1 = metaA[j + 1]; const float w1 = metaW[j + 1];
        agg_step(m0, w0, lane, node_msg, rel_msg, dt_msg, a0, a1);
        agg_step(m1, w1, lane, node_msg, rel_msg, dt_msg, a0, a1);
    }
    if (j < hi)
        agg_step(metaA[j], metaW[j], lane, node_msg, rel_msg, dt_msg, a0, a1);

    ((float2*)(out + (size_t)n * OUT_DIM))[lane] = make_float2(a0, a1);
}

// ---------------------------------------------------------------------------
// Fallback: single-pass atomic edge kernel (known-good round-6 style).
// ---------------------------------------------------------------------------
__global__ __launch_bounds__(256) void edge_atomic_kernel(
    const int* __restrict__ edges, const int* __restrict__ q_tau,
    const ushort_t* __restrict__ node_attn, const ushort_t* __restrict__ node_msg,
    const ushort_t* __restrict__ rel_attn,  const ushort_t* __restrict__ rel_msg,
    const ushort_t* __restrict__ dt_attn,   const ushort_t* __restrict__ dt_msg,
    const ushort_t* __restrict__ Xqr,
    const float* __restrict__ w_alpha_W, const float* __restrict__ w_alpha_b,
    const int* __restrict__ flag, float* __restrict__ out)
{
    const int lane = threadIdx.x & 63;
    const int e    = blockIdx.x * 4 + (threadIdx.x >> 6);
    const int i64  = flag[0];

    int r, rel, tau, sub, obj;
    parse_edge(edges, e, i64, r, rel, tau, sub, obj);
    const int tq = q_tau[i64 ? 2 * r : r];
    if (tau < 0) tau = tq;
    const int di = clampi(tau - tq + 365, 0, N_DT - 1);

    const float xs = bu2f(node_attn[(size_t)sub * ATTN_DIM + lane]);
    const float xr = bu2f(rel_attn[(size_t)rel * ATTN_DIM + lane]);
    const float xt = bu2f(dt_attn[(size_t)di  * ATTN_DIM + lane]);
    const float xq = bu2f(Xqr[(size_t)r * ATTN_DIM + lane]);

    float v = fmaxf(xs + xr + xq + xt, 0.f) * w_alpha_W[lane];
    #pragma unroll
    for (int off = 32; off > 0; off >>= 1)
        v += __shfl_down(v, off, 64);
    v = __shfl(v, 0, 64);
    const float alpha = 1.f / (1.f + __expf(-(v + w_alpha_b[0])));

    const uint_t am = *(const uint_t*)(node_msg + (size_t)sub * 128 + 2 * lane);
    const uint_t bm = *(const uint_t*)(rel_msg  + (size_t)rel * 128 + 2 * lane);
    const uint_t tm = *(const uint_t*)(dt_msg   + (size_t)di  * 128 + 2 * lane);
    const float mx = blo(am) + blo(bm) + blo(tm);
    const float my = bhi(am) + bhi(bm) + bhi(tm);

    float* dst = out + (size_t)obj * OUT_DIM;
    atomicAdd(dst + 2 * lane,     alpha * mx);
    atomicAdd(dst + 2 * lane + 1, alpha * my);
}

// ===========================================================================
extern "C" void kernel_launch(void* const* d_in, const int* in_sizes, int n_in,
                              void* d_out, int out_size, void* d_ws, size_t ws_size,
                              hipStream_t stream)
{
    const int*   q_rel  = (const int*)d_in[1];
    const int*   q_tau  = (const int*)d_in[2];
    const float* hidden = (const float*)d_in[3];
    const int*   edges  = (const int*)d_in[4];
    const float* rela   = (const float*)d_in[7];
    const float* Ws     = (const float*)d_in[8];
    const float* Wr     = (const float*)d_in[9];
    const float* WqrW   = (const float*)d_in[10];
    const float* Wqrb   = (const float*)d_in[11];
    const float* Wtau   = (const float*)d_in[12];
    const float* waW    = (const float*)d_in[13];
    const float* wab    = (const float*)d_in[14];
    const float* Wh     = (const float*)d_in[15];
    const float* wt1    = (const float*)d_in[16];
    const float* bt1    = (const float*)d_in[17];
    const float* wt2    = (const float*)d_in[18];
    const float* bt2    = (const float*)d_in[19];
    float* out = (float*)d_out;

    // --- workspace carve (256-B aligned chunks) ---
    char* p = (char*)d_ws;
    size_t off = 0;
    auto carve = [&](size_t bytes) {
        char* q = p + off;
        off = (off + bytes + 255) & ~(size_t)255;
        return q;
    };
    int*      flag      = (int*)     carve(64);
    ushort_t* XqrB      = (ushort_t*)carve((size_t)N_QUERY * ATTN_DIM * 2);
    ushort_t* rel_attn  = (ushort_t*)carve((size_t)N_RELV * ATTN_DIM * 2);
    ushort_t* rel_msg   = (ushort_t*)carve((size_t)N_RELV * OUT_DIM * 2);
    ushort_t* dt_attn   = (ushort_t*)carve((size_t)N_DT * ATTN_DIM * 2);
    ushort_t* dt_msg    = (ushort_t*)carve((size_t)N_DT * OUT_DIM * 2);
    ushort_t* node_attn = (ushort_t*)carve((size_t)N_NODE * ATTN_DIM * 2);
    ushort_t* node_msg  = (ushort_t*)carve((size_t)N_NODE * OUT_DIM * 2);
    int*      deg       = (int*)     carve((size_t)N_NODE * 4);
    int*      offs      = (int*)     carve(((size_t)N_NODE + 1) * 4);
    int*      cursor    = (int*)     carve((size_t)N_NODE * 4);
    int*      chunksum  = (int*)     carve(256 * 4);
    int*      chunkbase = (int*)     carve(256 * 4);
    int2*     metaA     = (int2*)    carve((size_t)N_EDGE * 8);
    float*    metaW     = (float*)   carve((size_t)N_EDGE * 4);
    const size_t need_csr = off;

    detect_kernel<<<1, 256, 0, stream>>>(edges, flag);

    // shared precompute (both paths)
    node_tab_mfma<<<(N_NODE + 63) / 64, 256, 0, stream>>>(hidden, Ws, Wh,
                                                          node_attn, node_msg);
    rel_tab_kernel<<<N_RELV, 128, 0, stream>>>(rela, Wr, Wh, rel_attn, rel_msg);
    dt_tab_kernel <<<N_DT,   128, 0, stream>>>(wt1, bt1, wt2, bt2, Wtau, Wh,
                                               dt_attn, dt_msg);
    qr_tab_kernel <<<N_QUERY, 64, 0, stream>>>(rela, q_rel, WqrW, Wqrb, flag, XqrB);

    if (ws_size >= need_csr) {
        (void)hipMemsetAsync(deg, 0, (size_t)N_NODE * 4, stream);
        hist_kernel  <<<(N_EDGE + 255) / 256, 256, 0, stream>>>(edges, flag, deg);
        scan_a_kernel<<<NCH, 256, 0, stream>>>(deg, offs, chunksum);
        scan_b_kernel<<<1,   256, 0, stream>>>(chunksum, chunkbase, offs);
        scan_c_kernel<<<NCH, 256, 0, stream>>>(chunkbase, offs, cursor);
        alpha_kernel <<<N_EDGE / 16, 256, 0, stream>>>(edges, q_tau, node_attn,
                                                       rel_attn, dt_attn, XqrB,
                                                       waW, wab, flag, cursor,
                                                       metaA, metaW);
        agg_kernel   <<<N_NODE / 4, 256, 0, stream>>>(offs, metaA, metaW,
                                                      node_msg, rel_msg, dt_msg, out);
    } else {
        (void)hipMemsetAsync(out, 0, (size_t)out_size * sizeof(float), stream);
        edge_atomic_kernel<<<N_EDGE / 4, 256, 0, stream>>>(edges, q_tau,
                                                           node_attn, node_msg,
                                                           rel_attn, rel_msg,
                                                           dt_attn, dt_msg, XqrB,
                                                           waW, wab, flag, out);
    }
}

// Round 9
// 290.048 us; speedup vs baseline: 2.4350x; 1.0677x over previous
//
#include <hip/hip_runtime.h>

#define IN_DIM   128
#define OUT_DIM  128
#define ATTN_DIM 64
#define N_RELV   401
#define N_NODE   50000
#define N_EDGE   500000
#define N_QUERY  64
#define N_DT     731
#define NCH      196      // ceil(50000/256) scan chunks

typedef unsigned short ushort_t;
typedef unsigned int   uint_t;
typedef __attribute__((ext_vector_type(8))) short v8s;   // 8 bf16 (4 VGPRs)
typedef __attribute__((ext_vector_type(4))) float v4f;

__device__ __forceinline__ int clampi(int v, int lo, int hi) {
    return v < lo ? lo : (v > hi ? hi : v);
}
__device__ __forceinline__ float bu2f(ushort_t u) {
    union { uint_t i; float f; } v; v.i = ((uint_t)u) << 16; return v.f;
}
__device__ __forceinline__ float blo(uint_t u) { return bu2f((ushort_t)(u & 0xffff)); }
__device__ __forceinline__ float bhi(uint_t u) { return bu2f((ushort_t)(u >> 16)); }
__device__ __forceinline__ ushort_t f2bu(float f) {   // RNE, finite inputs
    union { float f; uint_t i; } v; v.f = f;
    const uint_t x = v.i;
    return (ushort_t)((x + 0x7fffu + ((x >> 16) & 1u)) >> 16);
}

// edge parse (int32 vs int64 rows)
__device__ __forceinline__ void parse_edge(const int* __restrict__ edges, int e,
                                           int i64, int& r, int& rel, int& tau,
                                           int& sub, int& obj) {
    if (i64) {
        const int* E = edges + (size_t)e * 14;
        r = E[0]; rel = E[4]; tau = E[8]; sub = E[10]; obj = E[12];
    } else {
        const int* E = edges + (size_t)e * 7;
        r = E[0]; rel = E[2]; tau = E[4]; sub = E[5]; obj = E[6];
    }
    r   = clampi(r,   0, N_QUERY - 1);
    rel = clampi(rel, 0, N_RELV - 1);
    sub = clampi(sub, 0, N_NODE - 1);
    obj = clampi(obj, 0, N_NODE - 1);
}

// ---------------------------------------------------------------------------
__global__ __launch_bounds__(256) void detect_kernel(
    const int* __restrict__ edges, int* __restrict__ flag)
{
    __shared__ int bad;
    if (threadIdx.x == 0) bad = 0;
    __syncthreads();
    for (int i = threadIdx.x; i < 1000; i += 256) {
        const int w = edges[2 * i + 1];
        if (w != 0 && w != -1) bad = 1;
    }
    __syncthreads();
    if (threadIdx.x == 0) flag[0] = (bad == 0) ? 1 : 0;
}

// ---------------------------------------------------------------------------
// One-time: WTb[n][k] = bf16( n<64 ? Ws[k][n] : Wh[k][n-64] )   (192 x 128)
// ---------------------------------------------------------------------------
__global__ __launch_bounds__(256) void wt_prep_kernel(
    const float* __restrict__ Ws, const float* __restrict__ Wh,
    ushort_t* __restrict__ WTb)
{
    const int i = blockIdx.x * 256 + threadIdx.x;   // 96 blocks x 256 = 24576
    const int n = i >> 7, k = i & 127;
    const float w = (n < 64) ? Ws[k * 64 + n] : Wh[k * 128 + (n - 64)];
    WTb[i] = f2bu(w);
}

// ---------------------------------------------------------------------------
// MFMA node projection, LDS-free:
//   [node_attn | node_msg] = hidden @ [Ws | Wh]  (bf16 out)
// Block = 4 waves = 64 node rows; wave owns 16 rows. A fragments are
// converted fp32->bf16 straight from coalesced global loads (per MFMA the
// 64 lanes cover 16 rows x 128 B contiguous); B fragments load from WTb
// (L1/L2-resident). Same verified fragment/D mapping as before.
// ---------------------------------------------------------------------------
__global__ __launch_bounds__(256) void node_tab_mfma(
    const float* __restrict__ hidden, const ushort_t* __restrict__ WTb,
    ushort_t* __restrict__ node_attn, ushort_t* __restrict__ node_msg)
{
    const int tid  = threadIdx.x;
    const int wid  = tid >> 6;
    const int lane = tid & 63;
    const int m16  = lane & 15;
    const int q    = lane >> 4;
    const int nb   = blockIdx.x * 64;
    const int row  = nb + wid * 16 + m16;
    const int rowc = row < N_NODE ? row : N_NODE - 1;   // tail clamp (D guarded)

    v8s afr[4];
    #pragma unroll
    for (int c = 0; c < 4; ++c) {
        const float4 f0 = *(const float4*)(hidden + (size_t)rowc * 128 + 32 * c + 8 * q);
        const float4 f1 = *(const float4*)(hidden + (size_t)rowc * 128 + 32 * c + 8 * q + 4);
        v8s a;
        a[0] = (short)f2bu(f0.x); a[1] = (short)f2bu(f0.y);
        a[2] = (short)f2bu(f0.z); a[3] = (short)f2bu(f0.w);
        a[4] = (short)f2bu(f1.x); a[5] = (short)f2bu(f1.y);
        a[6] = (short)f2bu(f1.z); a[7] = (short)f2bu(f1.w);
        afr[c] = a;
    }

    #pragma unroll
    for (int t = 0; t < 12; ++t) {
        v4f acc = {0.f, 0.f, 0.f, 0.f};
        #pragma unroll
        for (int c = 0; c < 4; ++c) {
            const v8s bfr = *(const v8s*)(WTb + (size_t)(16 * t + m16) * 128 + 32 * c + 8 * q);
            acc = __builtin_amdgcn_mfma_f32_16x16x32_bf16(afr[c], bfr, acc, 0, 0, 0);
        }
        #pragma unroll
        for (int r = 0; r < 4; ++r) {
            const int node = nb + wid * 16 + 4 * q + r;
            if (node < N_NODE) {
                const int col = 16 * t + m16;
                if (col < 64) node_attn[(size_t)node * 64  + col]        = f2bu(acc[r]);
                else          node_msg [(size_t)node * 128 + (col - 64)] = f2bu(acc[r]);
            }
        }
    }
}

// ---------------------------------------------------------------------------
__global__ __launch_bounds__(128) void rel_tab_kernel(
    const float* __restrict__ rela, const float* __restrict__ Wr,
    const float* __restrict__ Wh,
    ushort_t* __restrict__ rel_attn, ushort_t* __restrict__ rel_msg)
{
    const int r = blockIdx.x, tid = threadIdx.x;
    __shared__ float h[IN_DIM];
    h[tid] = rela[(size_t)r * IN_DIM + tid];
    __syncthreads();

    if (tid < ATTN_DIM) {
        float a = 0.f;
        #pragma unroll 8
        for (int d = 0; d < IN_DIM; ++d) a += h[d] * Wr[d * ATTN_DIM + tid];
        rel_attn[(size_t)r * ATTN_DIM + tid] = f2bu(a);
    }
    float m = 0.f;
    #pragma unroll 8
    for (int d = 0; d < IN_DIM; ++d) m += h[d] * Wh[d * OUT_DIM + tid];
    rel_msg[(size_t)r * OUT_DIM + tid] = f2bu(m);
}

// ---------------------------------------------------------------------------
__global__ __launch_bounds__(128) void dt_tab_kernel(
    const float* __restrict__ wt1, const float* __restrict__ bt1,
    const float* __restrict__ wt2, const float* __restrict__ bt2,
    const float* __restrict__ Wtau, const float* __restrict__ Wh,
    ushort_t* __restrict__ dt_attn, ushort_t* __restrict__ dt_msg)
{
    const int i = blockIdx.x, tid = threadIdx.x;
    const float dt = (float)(i - 365);
    __shared__ float h[IN_DIM];
    h[tid] = wt1[tid] * dt + bt1[tid] + sinf(wt2[tid] * dt + bt2[tid]);
    __syncthreads();

    if (tid < ATTN_DIM) {
        float a = 0.f;
        #pragma unroll 8
        for (int d = 0; d < IN_DIM; ++d) a += h[d] * Wtau[d * ATTN_DIM + tid];
        dt_attn[(size_t)i * ATTN_DIM + tid] = f2bu(a);
    }
    float m = 0.f;
    #pragma unroll 8
    for (int d = 0; d < IN_DIM; ++d) m += h[d] * Wh[d * OUT_DIM + tid];
    dt_msg[(size_t)i * OUT_DIM + tid] = f2bu(m);
}

// ---------------------------------------------------------------------------
__global__ __launch_bounds__(64) void qr_tab_kernel(
    const float* __restrict__ rela, const int* __restrict__ q_rel,
    const float* __restrict__ W, const float* __restrict__ bias,
    const int* __restrict__ flag, ushort_t* __restrict__ Xqr)
{
    const int q = blockIdx.x, lane = threadIdx.x;
    const int i64 = flag[0];
    const int rel = clampi(q_rel[i64 ? 2 * q : q], 0, N_RELV - 1);

    __shared__ float h[IN_DIM];
    const float2 v = ((const float2*)(rela + (size_t)rel * IN_DIM))[lane];
    h[2 * lane] = v.x; h[2 * lane + 1] = v.y;
    __syncthreads();

    float acc = bias[lane];
    #pragma unroll 8
    for (int d = 0; d < IN_DIM; ++d) acc += h[d] * W[d * ATTN_DIM + lane];
    Xqr[(size_t)q * ATTN_DIM + lane] = f2bu(acc);
}

// ---------------------------------------------------------------------------
// CSR build
// ---------------------------------------------------------------------------
__global__ __launch_bounds__(256) void hist_kernel(
    const int* __restrict__ edges, const int* __restrict__ flag,
    int* __restrict__ deg)
{
    const int e = blockIdx.x * 256 + threadIdx.x;
    if (e >= N_EDGE) return;
    const int i64 = flag[0];
    int obj = i64 ? edges[(size_t)e * 14 + 12] : edges[(size_t)e * 7 + 6];
    obj = clampi(obj, 0, N_NODE - 1);
    atomicAdd(&deg[obj], 1);
}

__global__ __launch_bounds__(256) void scan_a_kernel(
    const int* __restrict__ deg, int* __restrict__ offs, int* __restrict__ chunksum)
{
    const int i = blockIdx.x * 256 + threadIdx.x;
    const int v = (i < N_NODE) ? deg[i] : 0;
    __shared__ int s[256];
    int acc = v;
    s[threadIdx.x] = acc; __syncthreads();
    #pragma unroll
    for (int off = 1; off < 256; off <<= 1) {
        const int t = (threadIdx.x >= off) ? s[threadIdx.x - off] : 0;
        __syncthreads();
        acc += t; s[threadIdx.x] = acc;
        __syncthreads();
    }
    if (i < N_NODE) offs[i] = acc - v;
    if (threadIdx.x == 255) chunksum[blockIdx.x] = acc;
}

__global__ __launch_bounds__(256) void scan_b_kernel(
    const int* __restrict__ chunksum, int* __restrict__ chunkbase,
    int* __restrict__ offs)
{
    const int b = threadIdx.x;
    const int v = (b < NCH) ? chunksum[b] : 0;
    __shared__ int s[256];
    int acc = v;
    s[b] = acc; __syncthreads();
    #pragma unroll
    for (int off = 1; off < 256; off <<= 1) {
        const int t = (b >= off) ? s[b - off] : 0;
        __syncthreads();
        acc += t; s[b] = acc;
        __syncthreads();
    }
    if (b < NCH) chunkbase[b] = acc - v;
    if (b == 0) offs[N_NODE] = N_EDGE;
}

__global__ __launch_bounds__(256) void scan_c_kernel(
    const int* __restrict__ chunkbase, int* __restrict__ offs,
    int* __restrict__ cursor)
{
    const int i = blockIdx.x * 256 + threadIdx.x;
    if (i >= N_NODE) return;
    const int o = offs[i] + chunkbase[blockIdx.x];
    offs[i] = o;
    cursor[i] = o;
}

// ---------------------------------------------------------------------------
// Phase 1: per-edge alpha. 16 lanes per edge (4 edges/wave).
// meta.x = sub | (di<<17), meta.y = rel, metaW = alpha.
// ---------------------------------------------------------------------------
__global__ __launch_bounds__(256) void alpha_kernel(
    const int* __restrict__ edges, const int* __restrict__ q_tau,
    const ushort_t* __restrict__ node_attn, const ushort_t* __restrict__ rel_attn,
    const ushort_t* __restrict__ dt_attn,  const ushort_t* __restrict__ Xqr,
    const float* __restrict__ w_alpha_W, const float* __restrict__ w_alpha_b,
    const int* __restrict__ flag, int* __restrict__ cursor,
    int2* __restrict__ metaA, float* __restrict__ metaW)
{
    const int g   = threadIdx.x & 15;
    const int e   = blockIdx.x * 16 + (threadIdx.x >> 4);
    const int i64 = flag[0];

    int r, rel, tau, sub, obj;
    parse_edge(edges, e, i64, r, rel, tau, sub, obj);
    const int tq = q_tau[i64 ? 2 * r : r];
    if (tau < 0) tau = tq;
    const int di = clampi(tau - tq + 365, 0, N_DT - 1);

    const uint2 xs = *(const uint2*)(node_attn + (size_t)sub * ATTN_DIM + 4 * g);
    const uint2 xr = *(const uint2*)(rel_attn + (size_t)rel * ATTN_DIM + 4 * g);
    const uint2 xt = *(const uint2*)(dt_attn  + (size_t)di  * ATTN_DIM + 4 * g);
    const uint2 xq = *(const uint2*)(Xqr      + (size_t)r   * ATTN_DIM + 4 * g);
    const float4 w = *(const float4*)(w_alpha_W + 4 * g);

    const float s0 = blo(xs.x) + blo(xr.x) + blo(xt.x) + blo(xq.x);
    const float s1 = bhi(xs.x) + bhi(xr.x) + bhi(xt.x) + bhi(xq.x);
    const float s2 = blo(xs.y) + blo(xr.y) + blo(xt.y) + blo(xq.y);
    const float s3 = bhi(xs.y) + bhi(xr.y) + bhi(xt.y) + bhi(xq.y);

    float v = fmaxf(s0, 0.f) * w.x + fmaxf(s1, 0.f) * w.y
            + fmaxf(s2, 0.f) * w.z + fmaxf(s3, 0.f) * w.w;
    v += __shfl_down(v, 8, 16);
    v += __shfl_down(v, 4, 16);
    v += __shfl_down(v, 2, 16);
    v += __shfl_down(v, 1, 16);

    if (g == 0) {
        const float alpha = 1.f / (1.f + __expf(-(v + w_alpha_b[0])));
        const int pos = atomicAdd(&cursor[obj], 1);
        metaA[pos] = make_int2(sub | (di << 17), rel);
        metaW[pos] = alpha;
    }
}

// ---------------------------------------------------------------------------
// Phase 2: per-node aggregation, no atomics.
// ---------------------------------------------------------------------------
__device__ __forceinline__ void agg_step(
    int2 m, float al, int lane,
    const ushort_t* __restrict__ node_msg, const ushort_t* __restrict__ rel_msg,
    const ushort_t* __restrict__ dt_msg, float& a0, float& a1)
{
    const int sub = m.x & 0x1FFFF;
    const int di  = m.x >> 17;
    const int rel = m.y;
    const uint_t am = *(const uint_t*)(node_msg + (size_t)sub * 128 + 2 * lane);
    const uint_t bm = *(const uint_t*)(rel_msg  + (size_t)rel * 128 + 2 * lane);
    const uint_t tm = *(const uint_t*)(dt_msg   + (size_t)di  * 128 + 2 * lane);
    a0 += al * (blo(am) + blo(bm) + blo(tm));
    a1 += al * (bhi(am) + bhi(bm) + bhi(tm));
}

__global__ __launch_bounds__(256) void agg_kernel(
    const int* __restrict__ offs, const int2* __restrict__ metaA,
    const float* __restrict__ metaW,
    const ushort_t* __restrict__ node_msg, const ushort_t* __restrict__ rel_msg,
    const ushort_t* __restrict__ dt_msg, float* __restrict__ out)
{
    const int lane = threadIdx.x & 63;
    const int n    = blockIdx.x * 4 + (threadIdx.x >> 6);

    const int lo = offs[n], hi = offs[n + 1];
    float a0 = 0.f, a1 = 0.f;
    int j = lo;
    for (; j + 1 < hi; j += 2) {
        const int2 m0 = metaA[j];     const float w0 = metaW[j];
        const int2 m1 = metaA[j + 1]; const float w1 = metaW[j + 1];
        agg_step(m0, w0, lane, node_msg, rel_msg, dt_msg, a0, a1);
        agg_step(m1, w1, lane, node_msg, rel_msg, dt_msg, a0, a1);
    }
    if (j < hi)
        agg_step(metaA[j], metaW[j], lane, node_msg, rel_msg, dt_msg, a0, a1);

    ((float2*)(out + (size_t)n * OUT_DIM))[lane] = make_float2(a0, a1);
}

// ---------------------------------------------------------------------------
// Fallback: single-pass atomic edge kernel.
// ---------------------------------------------------------------------------
__global__ __launch_bounds__(256) void edge_atomic_kernel(
    const int* __restrict__ edges, const int* __restrict__ q_tau,
    const ushort_t* __restrict__ node_attn, const ushort_t* __restrict__ node_msg,
    const ushort_t* __restrict__ rel_attn,  const ushort_t* __restrict__ rel_msg,
    const ushort_t* __restrict__ dt_attn,   const ushort_t* __restrict__ dt_msg,
    const ushort_t* __restrict__ Xqr,
    const float* __restrict__ w_alpha_W, const float* __restrict__ w_alpha_b,
    const int* __restrict__ flag, float* __restrict__ out)
{
    const int lane = threadIdx.x & 63;
    const int e    = blockIdx.x * 4 + (threadIdx.x >> 6);
    const int i64  = flag[0];

    int r, rel, tau, sub, obj;
    parse_edge(edges, e, i64, r, rel, tau, sub, obj);
    const int tq = q_tau[i64 ? 2 * r : r];
    if (tau < 0) tau = tq;
    const int di = clampi(tau - tq + 365, 0, N_DT - 1);

    const float xs = bu2f(node_attn[(size_t)sub * ATTN_DIM + lane]);
    const float xr = bu2f(rel_attn[(size_t)rel * ATTN_DIM + lane]);
    const float xt = bu2f(dt_attn[(size_t)di  * ATTN_DIM + lane]);
    const float xq = bu2f(Xqr[(size_t)r * ATTN_DIM + lane]);

    float v = fmaxf(xs + xr + xq + xt, 0.f) * w_alpha_W[lane];
    #pragma unroll
    for (int off = 32; off > 0; off >>= 1)
        v += __shfl_down(v, off, 64);
    v = __shfl(v, 0, 64);
    const float alpha = 1.f / (1.f + __expf(-(v + w_alpha_b[0])));

    const uint_t am = *(const uint_t*)(node_msg + (size_t)sub * 128 + 2 * lane);
    const uint_t bm = *(const uint_t*)(rel_msg  + (size_t)rel * 128 + 2 * lane);
    const uint_t tm = *(const uint_t*)(dt_msg   + (size_t)di  * 128 + 2 * lane);
    const float mx = blo(am) + blo(bm) + blo(tm);
    const float my = bhi(am) + bhi(bm) + bhi(tm);

    float* dst = out + (size_t)obj * OUT_DIM;
    atomicAdd(dst + 2 * lane,     alpha * mx);
    atomicAdd(dst + 2 * lane + 1, alpha * my);
}

// ===========================================================================
extern "C" void kernel_launch(void* const* d_in, const int* in_sizes, int n_in,
                              void* d_out, int out_size, void* d_ws, size_t ws_size,
                              hipStream_t stream)
{
    const int*   q_rel  = (const int*)d_in[1];
    const int*   q_tau  = (const int*)d_in[2];
    const float* hidden = (const float*)d_in[3];
    const int*   edges  = (const int*)d_in[4];
    const float* rela   = (const float*)d_in[7];
    const float* Ws     = (const float*)d_in[8];
    const float* Wr     = (const float*)d_in[9];
    const float* WqrW   = (const float*)d_in[10];
    const float* Wqrb   = (const float*)d_in[11];
    const float* Wtau   = (const float*)d_in[12];
    const float* waW    = (const float*)d_in[13];
    const float* wab    = (const float*)d_in[14];
    const float* Wh     = (const float*)d_in[15];
    const float* wt1    = (const float*)d_in[16];
    const float* bt1    = (const float*)d_in[17];
    const float* wt2    = (const float*)d_in[18];
    const float* bt2    = (const float*)d_in[19];
    float* out = (float*)d_out;

    // --- workspace carve (256-B aligned chunks) ---
    char* p = (char*)d_ws;
    size_t off = 0;
    auto carve = [&](size_t bytes) {
        char* q = p + off;
        off = (off + bytes + 255) & ~(size_t)255;
        return q;
    };
    int*      flag      = (int*)     carve(64);
    ushort_t* WTb       = (ushort_t*)carve((size_t)192 * 128 * 2);
    ushort_t* XqrB      = (ushort_t*)carve((size_t)N_QUERY * ATTN_DIM * 2);
    ushort_t* rel_attn  = (ushort_t*)carve((size_t)N_RELV * ATTN_DIM * 2);
    ushort_t* rel_msg   = (ushort_t*)carve((size_t)N_RELV * OUT_DIM * 2);
    ushort_t* dt_attn   = (ushort_t*)carve((size_t)N_DT * ATTN_DIM * 2);
    ushort_t* dt_msg    = (ushort_t*)carve((size_t)N_DT * OUT_DIM * 2);
    ushort_t* node_attn = (ushort_t*)carve((size_t)N_NODE * ATTN_DIM * 2);
    ushort_t* node_msg  = (ushort_t*)carve((size_t)N_NODE * OUT_DIM * 2);
    int*      deg       = (int*)     carve((size_t)N_NODE * 4);
    int*      offs      = (int*)     carve(((size_t)N_NODE + 1) * 4);
    int*      cursor    = (int*)     carve((size_t)N_NODE * 4);
    int*      chunksum  = (int*)     carve(256 * 4);
    int*      chunkbase = (int*)     carve(256 * 4);
    int2*     metaA     = (int2*)    carve((size_t)N_EDGE * 8);
    float*    metaW     = (float*)   carve((size_t)N_EDGE * 4);
    const size_t need_csr = off;

    detect_kernel<<<1, 256, 0, stream>>>(edges, flag);

    // shared precompute (both paths)
    wt_prep_kernel<<<96, 256, 0, stream>>>(Ws, Wh, WTb);
    node_tab_mfma<<<(N_NODE + 63) / 64, 256, 0, stream>>>(hidden, WTb,
                                                          node_attn, node_msg);
    rel_tab_kernel<<<N_RELV, 128, 0, stream>>>(rela, Wr, Wh, rel_attn, rel_msg);
    dt_tab_kernel <<<N_DT,   128, 0, stream>>>(wt1, bt1, wt2, bt2, Wtau, Wh,
                                               dt_attn, dt_msg);
    qr_tab_kernel <<<N_QUERY, 64, 0, stream>>>(rela, q_rel, WqrW, Wqrb, flag, XqrB);

    if (ws_size >= need_csr) {
        (void)hipMemsetAsync(deg, 0, (size_t)N_NODE * 4, stream);
        hist_kernel  <<<(N_EDGE + 255) / 256, 256, 0, stream>>>(edges, flag, deg);
        scan_a_kernel<<<NCH, 256, 0, stream>>>(deg, offs, chunksum);
        scan_b_kernel<<<1,   256, 0, stream>>>(chunksum, chunkbase, offs);
        scan_c_kernel<<<NCH, 256, 0, stream>>>(chunkbase, offs, cursor);
        alpha_kernel <<<N_EDGE / 16, 256, 0, stream>>>(edges, q_tau, node_attn,
                                                       rel_attn, dt_attn, XqrB,
                                                       waW, wab, flag, cursor,
                                                       metaA, metaW);
        agg_kernel   <<<N_NODE / 4, 256, 0, stream>>>(offs, metaA, metaW,
                                                      node_msg, rel_msg, dt_msg, out);
    } else {
        (void)hipMemsetAsync(out, 0, (size_t)out_size * sizeof(float), stream);
        edge_atomic_kernel<<<N_EDGE / 4, 256, 0, stream>>>(edges, q_tau,
                                                           node_attn, node_msg,
                                                           rel_attn, rel_msg,
                                                           dt_attn, dt_msg, XqrB,
                                                           waW, wab, flag, out);
    }
}